// Round 5
// baseline (1373.114 us; speedup 1.0000x reference)
//
#include <hip/hip_runtime.h>

#define DD 64
#define SCAN_B 256
#define WPAD 68          // padded row for transposed W in LDS (16B-aligned, bank-balanced)
#define WMAT (DD * WPAD) // 4352 floats per matrix

__device__ __forceinline__ float lane_bcast(float x, int k) {
    return __int_as_float(__builtin_amdgcn_readlane(__float_as_int(x), k));
}

// ---------------- degree histogram (int) ----------------
__global__ void hist_kernel(const int* __restrict__ src, const int* __restrict__ dst,
                            int* __restrict__ outd, int* __restrict__ ind, int E) {
    int e = blockIdx.x * blockDim.x + threadIdx.x;
    if (e < E) {
        atomicAdd(&outd[src[e]], 1);
        atomicAdd(&ind[dst[e]], 1);
    }
}

// outn = rsqrt(max(outdeg,1)); inn = rsqrt(max(indeg,1)); rs = sqrt(max(outdeg,1))
__global__ void norm_kernel(const int* __restrict__ outd, const int* __restrict__ ind,
                            float* __restrict__ outn, float* __restrict__ inn,
                            float* __restrict__ rs, int n) {
    int i = blockIdx.x * blockDim.x + threadIdx.x;
    if (i < n) {
        float od = fmaxf((float)outd[i], 1.0f);
        outn[i] = rsqrtf(od);
        rs[i]   = sqrtf(od);
        inn[i]  = rsqrtf(fmaxf((float)ind[i], 1.0f));
    }
}

// ---------------- exclusive scan of in-degrees -> rowptr ----------------
__global__ void scan1_kernel(const int* __restrict__ in, int* __restrict__ out,
                             int* __restrict__ bsums, int n) {
    __shared__ int tmp[SCAN_B];
    int gid = blockIdx.x * SCAN_B + threadIdx.x;
    int v = (gid < n) ? in[gid] : 0;
    tmp[threadIdx.x] = v;
    __syncthreads();
    for (int off = 1; off < SCAN_B; off <<= 1) {
        int t = (threadIdx.x >= off) ? tmp[threadIdx.x - off] : 0;
        __syncthreads();
        tmp[threadIdx.x] += t;
        __syncthreads();
    }
    if (gid < n) out[gid] = tmp[threadIdx.x] - v;
    if (threadIdx.x == SCAN_B - 1) bsums[blockIdx.x] = tmp[SCAN_B - 1];
}

__global__ void scan2_kernel(int* __restrict__ bsums, int nb) {
    __shared__ int tmp[512];
    int v = (threadIdx.x < nb) ? bsums[threadIdx.x] : 0;
    tmp[threadIdx.x] = v;
    __syncthreads();
    for (int off = 1; off < 512; off <<= 1) {
        int t = (threadIdx.x >= off) ? tmp[threadIdx.x - off] : 0;
        __syncthreads();
        tmp[threadIdx.x] += t;
        __syncthreads();
    }
    if (threadIdx.x < nb) bsums[threadIdx.x] = tmp[threadIdx.x] - v;
}

__global__ void scan3_kernel(int* __restrict__ out, const int* __restrict__ bsums,
                             int n, int E) {
    int gid = blockIdx.x * SCAN_B + threadIdx.x;
    if (gid < n) out[gid] += bsums[blockIdx.x];
    if (gid == 0) out[n] = E;
}

// ---------------- CSR fill: edges grouped by dst ----------------
__global__ void fill_kernel(const int* __restrict__ src, const int* __restrict__ dst,
                            const int* __restrict__ rowptr, int* __restrict__ cnt,
                            int* __restrict__ esrc, int E) {
    int e = blockIdx.x * blockDim.x + threadIdx.x;
    if (e < E) {
        int d = dst[e];
        int p = rowptr[d] + atomicAdd(&cnt[d], 1);
        esrc[p] = src[e];
    }
}

// ---------------- pre-scale: hs = feats * outn ----------------
__global__ void scale_kernel(const float* __restrict__ feats, const float* __restrict__ outn,
                             float* __restrict__ hs, int n) {
    int idx = blockIdx.x * blockDim.x + threadIdx.x;   // one float4 per thread
    if (idx < n * (DD / 4)) {
        int v = idx >> 4;
        float s = outn[v];
        float4 f = ((const float4*)feats)[idx];
        f.x *= s; f.y *= s; f.z *= s; f.w *= s;
        ((float4*)hs)[idx] = f;
    }
}

// ---------------- fused per-layer: CSR gather + dual matvec + LN + relu + JK ----------------
// hs_in is the SCALED previous-layer output (h * outn). hs_in must not alias hs_out.
// grid MUST be <= 3 blocks/CU co-resident (launch with 768 blocks).
__global__ __launch_bounds__(512, 6) void gcn_kernel(
    const int* __restrict__ rowptr, const int* __restrict__ esrc,
    const float* __restrict__ inn, const float* __restrict__ rs,
    const float* __restrict__ outn,
    const float* __restrict__ hs_in,
    const float* __restrict__ Wc, const float* __restrict__ bc,
    const float* __restrict__ Wr, const float* __restrict__ br,
    const float* __restrict__ g, const float* __restrict__ bb,
    float* __restrict__ hs_out, float* __restrict__ h_final,
    int first, int n)
{
    __shared__ float sW[2 * WMAT];   // transposed: sW[j*WPAD + k] = W[k*DD + j]
    for (int idx = threadIdx.x; idx < DD * DD; idx += blockDim.x) {
        int k = idx >> 6, j = idx & 63;
        sW[j * WPAD + k]        = Wc[idx];
        sW[WMAT + j * WPAD + k] = Wr[idx];
    }
    __syncthreads();

    int lane = threadIdx.x & 63;
    int wave = threadIdx.x >> 6;
    int stride = (gridDim.x * blockDim.x) >> 6;
    const float4* wcl = (const float4*)&sW[lane * WPAD];
    const float4* wrl = (const float4*)&sW[WMAT + lane * WPAD];
    float bias = bc[lane] + br[lane];
    float gl = g[lane], bbl = bb[lane];

    int v = blockIdx.x * (blockDim.x >> 6) + wave;
    // prologue: index prefetch for first node
    int start = 0, deg = 0, eidx = 0;
    if (v < n) {
        start = rowptr[v];
        deg = rowptr[v + 1] - start;
        eidx = (lane < min(deg, 64)) ? esrc[start + lane] : 0;
    }

    while (v < n) {
        // ---- prefetch next node's indices (overlaps current node's work) ----
        int vn = v + stride;
        int startN = 0, degN = 0, eidxN = 0;
        if (vn < n) {
            startN = rowptr[vn];
            degN = rowptr[vn + 1] - startN;
            eidxN = (lane < min(degN, 64)) ? esrc[startN + lane] : 0;
        }

        // ---- gather over in-edges: xa = sum hs_in[src] (already outn-scaled) ----
        float xa = 0.0f;
        int m = min(deg, 64);
        int j = 0;
        for (; j + 3 < m; j += 4) {
            int s0 = __builtin_amdgcn_readlane(eidx, j);
            int s1 = __builtin_amdgcn_readlane(eidx, j + 1);
            int s2 = __builtin_amdgcn_readlane(eidx, j + 2);
            int s3 = __builtin_amdgcn_readlane(eidx, j + 3);
            float a0 = hs_in[(size_t)s0 * DD + lane];
            float a1 = hs_in[(size_t)s1 * DD + lane];
            float a2 = hs_in[(size_t)s2 * DD + lane];
            float a3 = hs_in[(size_t)s3 * DD + lane];
            xa += (a0 + a1) + (a2 + a3);
        }
        for (; j < m; ++j) {
            int s = __builtin_amdgcn_readlane(eidx, j);
            xa += hs_in[(size_t)s * DD + lane];
        }
        if (deg > 64) {  // rare slow path
            for (int base = 64; base < deg; base += 64) {
                int mm = min(64, deg - base);
                int ei = (lane < mm) ? esrc[start + base + lane] : 0;
                for (int jj = 0; jj < mm; ++jj) {
                    int s = __builtin_amdgcn_readlane(ei, jj);
                    xa += hs_in[(size_t)s * DD + lane];
                }
            }
        }
        xa *= inn[v];
        float xh = hs_in[(size_t)v * DD + lane] * rs[v];  // unscale self row

        // ---- dual matvec: readlane broadcast + LDS float4 weight reads ----
        float acc = bias;
        #pragma unroll
        for (int kk = 0; kk < 16; ++kk) {
            float4 wc4 = wcl[kk];
            float4 wr4 = wrl[kk];
            acc = fmaf(lane_bcast(xa, 4 * kk + 0), wc4.x, acc);
            acc = fmaf(lane_bcast(xh, 4 * kk + 0), wr4.x, acc);
            acc = fmaf(lane_bcast(xa, 4 * kk + 1), wc4.y, acc);
            acc = fmaf(lane_bcast(xh, 4 * kk + 1), wr4.y, acc);
            acc = fmaf(lane_bcast(xa, 4 * kk + 2), wc4.z, acc);
            acc = fmaf(lane_bcast(xh, 4 * kk + 2), wr4.z, acc);
            acc = fmaf(lane_bcast(xa, 4 * kk + 3), wc4.w, acc);
            acc = fmaf(lane_bcast(xh, 4 * kk + 3), wr4.w, acc);
        }

        // ---- LayerNorm across 64 lanes + relu ----
        float s = acc;
        #pragma unroll
        for (int m2 = 32; m2 >= 1; m2 >>= 1) s += __shfl_xor(s, m2);
        float mu = s * (1.0f / 64.0f);
        float c = acc - mu;
        float vs = c * c;
        #pragma unroll
        for (int m2 = 32; m2 >= 1; m2 >>= 1) vs += __shfl_xor(vs, m2);
        float var = vs * (1.0f / 64.0f);
        float y = fmaxf(c * rsqrtf(var + 1e-5f) * gl + bbl, 0.0f);

        hs_out[(size_t)v * DD + lane] = y * outn[v];   // store pre-scaled for next gather
        h_final[(size_t)v * DD + lane] = first ? y : (h_final[(size_t)v * DD + lane] + y);

        v = vn; start = startN; deg = degN; eidx = eidxN;
    }
}

// ---------------- final prediction matvec (LDS weights) ----------------
__global__ __launch_bounds__(512) void pred_kernel(
    const float* __restrict__ h_final, const float* __restrict__ W,
    const float* __restrict__ b, float* __restrict__ out, int n)
{
    __shared__ float sW[WMAT];
    for (int idx = threadIdx.x; idx < DD * DD; idx += blockDim.x) {
        int k = idx >> 6, j = idx & 63;
        sW[j * WPAD + k] = W[idx];
    }
    __syncthreads();

    int lane = threadIdx.x & 63;
    int wave = threadIdx.x >> 6;
    int wavesTotal = (gridDim.x * blockDim.x) >> 6;
    const float4* wl = (const float4*)&sW[lane * WPAD];
    float bl = b[lane];

    for (int v = blockIdx.x * (blockDim.x >> 6) + wave; v < n; v += wavesTotal) {
        float xh = h_final[(size_t)v * DD + lane];
        float acc = bl;
        #pragma unroll
        for (int kk = 0; kk < 16; ++kk) {
            float4 w4 = wl[kk];
            acc = fmaf(lane_bcast(xh, 4 * kk + 0), w4.x, acc);
            acc = fmaf(lane_bcast(xh, 4 * kk + 1), w4.y, acc);
            acc = fmaf(lane_bcast(xh, 4 * kk + 2), w4.z, acc);
            acc = fmaf(lane_bcast(xh, 4 * kk + 3), w4.w, acc);
        }
        out[(size_t)v * DD + lane] = acc;
    }
}

extern "C" void kernel_launch(void* const* d_in, const int* in_sizes, int n_in,
                              void* d_out, int out_size, void* d_ws, size_t ws_size,
                              hipStream_t stream) {
    const float* feats  = (const float*)d_in[0];
    const int*   src    = (const int*)d_in[1];
    const int*   dst    = (const int*)d_in[2];
    const float* conv_W = (const float*)d_in[3];
    const float* conv_b = (const float*)d_in[4];
    const float* res_W  = (const float*)d_in[5];
    const float* res_b  = (const float*)d_in[6];
    const float* ln_g   = (const float*)d_in[7];
    const float* ln_b   = (const float*)d_in[8];
    const float* pred_W = (const float*)d_in[9];
    const float* pred_b = (const float*)d_in[10];

    int N = in_sizes[0] / DD;
    int E = in_sizes[1];
    int nb = (N + SCAN_B - 1) / SCAN_B;

    // workspace layout (~58.2 MB)
    int*   outd_i = (int*)d_ws;            // N
    int*   ind_i  = outd_i + N;            // N
    int*   cnt    = ind_i + N;             // N
    int*   rowptr = cnt + N;               // N+1
    int*   bsums  = rowptr + N + 1;        // 512
    int*   esrc   = bsums + 512;           // E
    float* outn   = (float*)(esrc + E);    // N
    float* inn    = outn + N;              // N
    float* rs     = inn + N;               // N
    float* hsA    = rs + N;                // N*DD  (scaled h ping)
    float* hfin   = hsA + (size_t)N * DD;  // N*DD
    float* hsB    = (float*)d_out;         // scaled h pong (pred overwrites last)

    hipMemsetAsync(outd_i, 0, (size_t)3 * N * sizeof(int), stream);

    hist_kernel<<<(E + 255) / 256, 256, 0, stream>>>(src, dst, outd_i, ind_i, E);
    norm_kernel<<<(N + 255) / 256, 256, 0, stream>>>(outd_i, ind_i, outn, inn, rs, N);

    scan1_kernel<<<nb, SCAN_B, 0, stream>>>(ind_i, rowptr, bsums, N);
    scan2_kernel<<<1, 512, 0, stream>>>(bsums, nb);
    scan3_kernel<<<nb, SCAN_B, 0, stream>>>(rowptr, bsums, N, E);
    fill_kernel<<<(E + 255) / 256, 256, 0, stream>>>(src, dst, rowptr, cnt, esrc, E);

    scale_kernel<<<(N * (DD / 4) + 255) / 256, 256, 0, stream>>>(feats, outn, hsA, N);

    // ping-pong (scaled): hsA -> hsB(d_out) -> hsA -> hsB(dead, pred overwrites)
    const float* ins[3]  = {hsA, hsB, hsA};
    float*       outs[3] = {hsB, hsA, hsB};
    for (int l = 0; l < 3; ++l) {
        gcn_kernel<<<768, 512, 0, stream>>>(
            rowptr, esrc, inn, rs, outn, ins[l],
            conv_W + (size_t)l * DD * DD, conv_b + (size_t)l * DD,
            res_W  + (size_t)l * DD * DD, res_b  + (size_t)l * DD,
            ln_g   + (size_t)l * DD,      ln_b   + (size_t)l * DD,
            outs[l], hfin, (l == 0) ? 1 : 0, N);
    }
    pred_kernel<<<768, 512, 0, stream>>>(hfin, pred_W, pred_b, (float*)d_out, N);
}

// Round 6
// 775.076 us; speedup vs baseline: 1.7716x; 1.7716x over previous
//
#include <hip/hip_runtime.h>

#define DD 64
#define SCAN_B 256
#define WPAD 68          // padded row for transposed W in LDS (16B-aligned, bank-balanced)
#define WMAT (DD * WPAD) // 4352 floats per matrix

__device__ __forceinline__ float lane_bcast(float x, int k) {
    return __int_as_float(__builtin_amdgcn_readlane(__float_as_int(x), k));
}

// ---------------- degree histogram (int) ----------------
__global__ void hist_kernel(const int* __restrict__ src, const int* __restrict__ dst,
                            int* __restrict__ outd, int* __restrict__ ind, int E) {
    int e = blockIdx.x * blockDim.x + threadIdx.x;
    if (e < E) {
        atomicAdd(&outd[src[e]], 1);
        atomicAdd(&ind[dst[e]], 1);
    }
}

// outn = rsqrt(max(outdeg,1)); inn = rsqrt(max(indeg,1)); rs = sqrt(max(outdeg,1))
__global__ void norm_kernel(const int* __restrict__ outd, const int* __restrict__ ind,
                            float* __restrict__ outn, float* __restrict__ inn,
                            float* __restrict__ rs, int n) {
    int i = blockIdx.x * blockDim.x + threadIdx.x;
    if (i < n) {
        float od = fmaxf((float)outd[i], 1.0f);
        outn[i] = rsqrtf(od);
        rs[i]   = sqrtf(od);
        inn[i]  = rsqrtf(fmaxf((float)ind[i], 1.0f));
    }
}

// ---------------- exclusive scan of in-degrees -> rowptr ----------------
__global__ void scan1_kernel(const int* __restrict__ in, int* __restrict__ out,
                             int* __restrict__ bsums, int n) {
    __shared__ int tmp[SCAN_B];
    int gid = blockIdx.x * SCAN_B + threadIdx.x;
    int v = (gid < n) ? in[gid] : 0;
    tmp[threadIdx.x] = v;
    __syncthreads();
    for (int off = 1; off < SCAN_B; off <<= 1) {
        int t = (threadIdx.x >= off) ? tmp[threadIdx.x - off] : 0;
        __syncthreads();
        tmp[threadIdx.x] += t;
        __syncthreads();
    }
    if (gid < n) out[gid] = tmp[threadIdx.x] - v;
    if (threadIdx.x == SCAN_B - 1) bsums[blockIdx.x] = tmp[SCAN_B - 1];
}

__global__ void scan2_kernel(int* __restrict__ bsums, int nb) {
    __shared__ int tmp[512];
    int v = (threadIdx.x < nb) ? bsums[threadIdx.x] : 0;
    tmp[threadIdx.x] = v;
    __syncthreads();
    for (int off = 1; off < 512; off <<= 1) {
        int t = (threadIdx.x >= off) ? tmp[threadIdx.x - off] : 0;
        __syncthreads();
        tmp[threadIdx.x] += t;
        __syncthreads();
    }
    if (threadIdx.x < nb) bsums[threadIdx.x] = tmp[threadIdx.x] - v;
}

__global__ void scan3_kernel(int* __restrict__ out, const int* __restrict__ bsums,
                             int n, int E) {
    int gid = blockIdx.x * SCAN_B + threadIdx.x;
    if (gid < n) out[gid] += bsums[blockIdx.x];
    if (gid == 0) out[n] = E;
}

// ---------------- CSR fill: edges grouped by dst ----------------
__global__ void fill_kernel(const int* __restrict__ src, const int* __restrict__ dst,
                            const int* __restrict__ rowptr, int* __restrict__ cnt,
                            int* __restrict__ esrc, int E) {
    int e = blockIdx.x * blockDim.x + threadIdx.x;
    if (e < E) {
        int d = dst[e];
        int p = rowptr[d] + atomicAdd(&cnt[d], 1);
        esrc[p] = src[e];
    }
}

// ---------------- pre-scale: hs = feats * outn ----------------
__global__ void scale_kernel(const float* __restrict__ feats, const float* __restrict__ outn,
                             float* __restrict__ hs, int n) {
    int idx = blockIdx.x * blockDim.x + threadIdx.x;   // one float4 per thread
    if (idx < n * (DD / 4)) {
        int v = idx >> 4;
        float s = outn[v];
        float4 f = ((const float4*)feats)[idx];
        f.x *= s; f.y *= s; f.z *= s; f.w *= s;
        ((float4*)hs)[idx] = f;
    }
}

// ---------------- fused per-layer: CSR gather + dual matvec + LN + relu + JK ----------------
// hs_in is the SCALED previous-layer output (h * outn). hs_in must not alias hs_out.
// Gather remap: lane = (stripe g = lane>>4, feat4 q = lane&15) -> 4 edges per float4 load.
// NO forced waves/EU clause: (512,6) in R5 forced VGPR->40 and spilled (+1 GB HBM traffic).
__global__ __launch_bounds__(512) void gcn_kernel(
    const int* __restrict__ rowptr, const int* __restrict__ esrc,
    const float* __restrict__ inn, const float* __restrict__ rs,
    const float* __restrict__ outn,
    const float* __restrict__ hs_in,
    const float* __restrict__ Wc, const float* __restrict__ bc,
    const float* __restrict__ Wr, const float* __restrict__ br,
    const float* __restrict__ g, const float* __restrict__ bb,
    float* __restrict__ hs_out, float* __restrict__ h_final,
    int first, int n)
{
    __shared__ float sW[2 * WMAT];   // transposed: sW[j*WPAD + k] = W[k*DD + j]
    for (int idx = threadIdx.x; idx < DD * DD; idx += blockDim.x) {
        int k = idx >> 6, j = idx & 63;
        sW[j * WPAD + k]        = Wc[idx];
        sW[WMAT + j * WPAD + k] = Wr[idx];
    }
    __syncthreads();

    int lane = threadIdx.x & 63;
    int wave = threadIdx.x >> 6;
    int stride = (gridDim.x * blockDim.x) >> 6;
    int q  = lane & 15;   // float4 feature group (features 4q..4q+3)
    int gg = lane >> 4;   // edge stripe 0..3
    const float4* wcl = (const float4*)&sW[lane * WPAD];
    const float4* wrl = (const float4*)&sW[WMAT + lane * WPAD];
    float bias = bc[lane] + br[lane];
    float gl = g[lane], bbl = bb[lane];

    int v = blockIdx.x * (blockDim.x >> 6) + wave;
    // prologue: index prefetch for first node
    int start = 0, deg = 0, eidx = 0;
    if (v < n) {
        start = rowptr[v];
        deg = rowptr[v + 1] - start;
        eidx = (lane < min(deg, 64)) ? esrc[start + lane] : 0;
    }

    while (v < n) {
        // ---- prefetch next node's indices (overlaps current node's work) ----
        int vn = v + stride;
        int startN = 0, degN = 0, eidxN = 0;
        if (vn < n) {
            startN = rowptr[vn];
            degN = rowptr[vn + 1] - startN;
            eidxN = (lane < min(degN, 64)) ? esrc[startN + lane] : 0;
        }

        // ---- gather: 4 edges per iteration via float4 row loads ----
        float4 xa4 = make_float4(0.f, 0.f, 0.f, 0.f);
        int m = min(deg, 64);
        for (int j = 0; j < m; j += 4) {
            int sv = __shfl(eidx, j + gg);                       // stripe's edge id
            float4 r = ((const float4*)(hs_in + (size_t)sv * DD))[q];
            float msk = (j + gg < m) ? 1.0f : 0.0f;
            xa4.x = fmaf(r.x, msk, xa4.x);
            xa4.y = fmaf(r.y, msk, xa4.y);
            xa4.z = fmaf(r.z, msk, xa4.z);
            xa4.w = fmaf(r.w, msk, xa4.w);
        }
        if (deg > 64) {  // rare slow path
            for (int base = 64; base < deg; base += 64) {
                int mm = min(64, deg - base);
                int ei = (lane < mm) ? esrc[start + base + lane] : 0;
                for (int j = 0; j < mm; j += 4) {
                    int sv = __shfl(ei, j + gg);
                    float4 r = ((const float4*)(hs_in + (size_t)sv * DD))[q];
                    float msk = (j + gg < mm) ? 1.0f : 0.0f;
                    xa4.x = fmaf(r.x, msk, xa4.x);
                    xa4.y = fmaf(r.y, msk, xa4.y);
                    xa4.z = fmaf(r.z, msk, xa4.z);
                    xa4.w = fmaf(r.w, msk, xa4.w);
                }
            }
        }
        // reduce across the 4 edge stripes (lanes 16/32 apart)
        xa4.x += __shfl_xor(xa4.x, 16); xa4.y += __shfl_xor(xa4.y, 16);
        xa4.z += __shfl_xor(xa4.z, 16); xa4.w += __shfl_xor(xa4.w, 16);
        xa4.x += __shfl_xor(xa4.x, 32); xa4.y += __shfl_xor(xa4.y, 32);
        xa4.z += __shfl_xor(xa4.z, 32); xa4.w += __shfl_xor(xa4.w, 32);

        float innv = inn[v];
        xa4.x *= innv; xa4.y *= innv; xa4.z *= innv; xa4.w *= innv;

        float rsv = rs[v];
        float4 xh4 = ((const float4*)(hs_in + (size_t)v * DD))[q];  // self row
        xh4.x *= rsv; xh4.y *= rsv; xh4.z *= rsv; xh4.w *= rsv;     // unscale

        // ---- dual matvec: feature k=4*kk+c lives in component c of lane kk ----
        float acc = bias;
        #pragma unroll
        for (int kk = 0; kk < 16; ++kk) {
            float4 wc4 = wcl[kk];
            float4 wr4 = wrl[kk];
            acc = fmaf(lane_bcast(xa4.x, kk), wc4.x, acc);
            acc = fmaf(lane_bcast(xh4.x, kk), wr4.x, acc);
            acc = fmaf(lane_bcast(xa4.y, kk), wc4.y, acc);
            acc = fmaf(lane_bcast(xh4.y, kk), wr4.y, acc);
            acc = fmaf(lane_bcast(xa4.z, kk), wc4.z, acc);
            acc = fmaf(lane_bcast(xh4.z, kk), wr4.z, acc);
            acc = fmaf(lane_bcast(xa4.w, kk), wc4.w, acc);
            acc = fmaf(lane_bcast(xh4.w, kk), wr4.w, acc);
        }

        // ---- LayerNorm across 64 lanes + relu ----
        float s = acc;
        #pragma unroll
        for (int m2 = 32; m2 >= 1; m2 >>= 1) s += __shfl_xor(s, m2);
        float mu = s * (1.0f / 64.0f);
        float c = acc - mu;
        float vs = c * c;
        #pragma unroll
        for (int m2 = 32; m2 >= 1; m2 >>= 1) vs += __shfl_xor(vs, m2);
        float var = vs * (1.0f / 64.0f);
        float y = fmaxf(c * rsqrtf(var + 1e-5f) * gl + bbl, 0.0f);

        hs_out[(size_t)v * DD + lane] = y * outn[v];   // store pre-scaled for next gather
        h_final[(size_t)v * DD + lane] = first ? y : (h_final[(size_t)v * DD + lane] + y);

        v = vn; start = startN; deg = degN; eidx = eidxN;
    }
}

// ---------------- final prediction matvec (LDS weights) ----------------
__global__ __launch_bounds__(512) void pred_kernel(
    const float* __restrict__ h_final, const float* __restrict__ W,
    const float* __restrict__ b, float* __restrict__ out, int n)
{
    __shared__ float sW[WMAT];
    for (int idx = threadIdx.x; idx < DD * DD; idx += blockDim.x) {
        int k = idx >> 6, j = idx & 63;
        sW[j * WPAD + k] = W[idx];
    }
    __syncthreads();

    int lane = threadIdx.x & 63;
    int wave = threadIdx.x >> 6;
    int wavesTotal = (gridDim.x * blockDim.x) >> 6;
    int q = lane & 15;
    const float4* wl = (const float4*)&sW[lane * WPAD];
    float bl = b[lane];

    for (int v = blockIdx.x * (blockDim.x >> 6) + wave; v < n; v += wavesTotal) {
        float4 xh4 = ((const float4*)(h_final + (size_t)v * DD))[q];
        float acc = bl;
        #pragma unroll
        for (int kk = 0; kk < 16; ++kk) {
            float4 w4 = wl[kk];
            acc = fmaf(lane_bcast(xh4.x, kk), w4.x, acc);
            acc = fmaf(lane_bcast(xh4.y, kk), w4.y, acc);
            acc = fmaf(lane_bcast(xh4.z, kk), w4.z, acc);
            acc = fmaf(lane_bcast(xh4.w, kk), w4.w, acc);
        }
        out[(size_t)v * DD + lane] = acc;
    }
}

extern "C" void kernel_launch(void* const* d_in, const int* in_sizes, int n_in,
                              void* d_out, int out_size, void* d_ws, size_t ws_size,
                              hipStream_t stream) {
    const float* feats  = (const float*)d_in[0];
    const int*   src    = (const int*)d_in[1];
    const int*   dst    = (const int*)d_in[2];
    const float* conv_W = (const float*)d_in[3];
    const float* conv_b = (const float*)d_in[4];
    const float* res_W  = (const float*)d_in[5];
    const float* res_b  = (const float*)d_in[6];
    const float* ln_g   = (const float*)d_in[7];
    const float* ln_b   = (const float*)d_in[8];
    const float* pred_W = (const float*)d_in[9];
    const float* pred_b = (const float*)d_in[10];

    int N = in_sizes[0] / DD;
    int E = in_sizes[1];
    int nb = (N + SCAN_B - 1) / SCAN_B;

    // workspace layout (~58.2 MB)
    int*   outd_i = (int*)d_ws;            // N
    int*   ind_i  = outd_i + N;            // N
    int*   cnt    = ind_i + N;             // N
    int*   rowptr = cnt + N;               // N+1
    int*   bsums  = rowptr + N + 1;        // 512
    int*   esrc   = bsums + 512;           // E
    float* outn   = (float*)(esrc + E);    // N
    float* inn    = outn + N;              // N
    float* rs     = inn + N;               // N
    float* hsA    = rs + N;                // N*DD  (scaled h ping)
    float* hfin   = hsA + (size_t)N * DD;  // N*DD
    float* hsB    = (float*)d_out;         // scaled h pong (pred overwrites last)

    hipMemsetAsync(outd_i, 0, (size_t)3 * N * sizeof(int), stream);

    hist_kernel<<<(E + 255) / 256, 256, 0, stream>>>(src, dst, outd_i, ind_i, E);
    norm_kernel<<<(N + 255) / 256, 256, 0, stream>>>(outd_i, ind_i, outn, inn, rs, N);

    scan1_kernel<<<nb, SCAN_B, 0, stream>>>(ind_i, rowptr, bsums, N);
    scan2_kernel<<<1, 512, 0, stream>>>(bsums, nb);
    scan3_kernel<<<nb, SCAN_B, 0, stream>>>(rowptr, bsums, N, E);
    fill_kernel<<<(E + 255) / 256, 256, 0, stream>>>(src, dst, rowptr, cnt, esrc, E);

    scale_kernel<<<(N * (DD / 4) + 255) / 256, 256, 0, stream>>>(feats, outn, hsA, N);

    // ping-pong (scaled): hsA -> hsB(d_out) -> hsA -> hsB(dead, pred overwrites)
    const float* ins[3]  = {hsA, hsB, hsA};
    float*       outs[3] = {hsB, hsA, hsB};
    for (int l = 0; l < 3; ++l) {
        gcn_kernel<<<768, 512, 0, stream>>>(
            rowptr, esrc, inn, rs, outn, ins[l],
            conv_W + (size_t)l * DD * DD, conv_b + (size_t)l * DD,
            res_W  + (size_t)l * DD * DD, res_b  + (size_t)l * DD,
            ln_g   + (size_t)l * DD,      ln_b   + (size_t)l * DD,
            outs[l], hfin, (l == 0) ? 1 : 0, N);
    }
    pred_kernel<<<768, 512, 0, stream>>>(hfin, pred_W, pred_b, (float*)d_out, N);
}

// Round 7
// 708.552 us; speedup vs baseline: 1.9379x; 1.0939x over previous
//
#include <hip/hip_runtime.h>

#define DD 64
#define SCAN_B 256
#define WPAD 68          // padded row for transposed W in LDS (16B-aligned, bank-balanced)
#define WMAT (DD * WPAD) // 4352 floats per matrix

__device__ __forceinline__ float lane_bcast(float x, int k) {
    return __int_as_float(__builtin_amdgcn_readlane(__float_as_int(x), k));
}

// ---------------- degree histogram (int) ----------------
__global__ void hist_kernel(const int* __restrict__ src, const int* __restrict__ dst,
                            int* __restrict__ outd, int* __restrict__ ind, int E) {
    int e = blockIdx.x * blockDim.x + threadIdx.x;
    if (e < E) {
        atomicAdd(&outd[src[e]], 1);
        atomicAdd(&ind[dst[e]], 1);
    }
}

// outn = rsqrt(max(outdeg,1)); inn = rsqrt(max(indeg,1)); rs = sqrt(max(outdeg,1))
__global__ void norm_kernel(const int* __restrict__ outd, const int* __restrict__ ind,
                            float* __restrict__ outn, float* __restrict__ inn,
                            float* __restrict__ rs, int n) {
    int i = blockIdx.x * blockDim.x + threadIdx.x;
    if (i < n) {
        float od = fmaxf((float)outd[i], 1.0f);
        outn[i] = rsqrtf(od);
        rs[i]   = sqrtf(od);
        inn[i]  = rsqrtf(fmaxf((float)ind[i], 1.0f));
    }
}

// ---------------- exclusive scan of in-degrees -> rowptr ----------------
__global__ void scan1_kernel(const int* __restrict__ in, int* __restrict__ out,
                             int* __restrict__ bsums, int n) {
    __shared__ int tmp[SCAN_B];
    int gid = blockIdx.x * SCAN_B + threadIdx.x;
    int v = (gid < n) ? in[gid] : 0;
    tmp[threadIdx.x] = v;
    __syncthreads();
    for (int off = 1; off < SCAN_B; off <<= 1) {
        int t = (threadIdx.x >= off) ? tmp[threadIdx.x - off] : 0;
        __syncthreads();
        tmp[threadIdx.x] += t;
        __syncthreads();
    }
    if (gid < n) out[gid] = tmp[threadIdx.x] - v;
    if (threadIdx.x == SCAN_B - 1) bsums[blockIdx.x] = tmp[SCAN_B - 1];
}

__global__ void scan2_kernel(int* __restrict__ bsums, int nb) {
    __shared__ int tmp[512];
    int v = (threadIdx.x < nb) ? bsums[threadIdx.x] : 0;
    tmp[threadIdx.x] = v;
    __syncthreads();
    for (int off = 1; off < 512; off <<= 1) {
        int t = (threadIdx.x >= off) ? tmp[threadIdx.x - off] : 0;
        __syncthreads();
        tmp[threadIdx.x] += t;
        __syncthreads();
    }
    if (threadIdx.x < nb) bsums[threadIdx.x] = tmp[threadIdx.x] - v;
}

__global__ void scan3_kernel(int* __restrict__ out, const int* __restrict__ bsums,
                             int n, int E) {
    int gid = blockIdx.x * SCAN_B + threadIdx.x;
    if (gid < n) out[gid] += bsums[blockIdx.x];
    if (gid == 0) out[n] = E;
}

// ---------------- CSR fill: edges grouped by dst ----------------
__global__ void fill_kernel(const int* __restrict__ src, const int* __restrict__ dst,
                            const int* __restrict__ rowptr, int* __restrict__ cnt,
                            int* __restrict__ esrc, int E) {
    int e = blockIdx.x * blockDim.x + threadIdx.x;
    if (e < E) {
        int d = dst[e];
        int p = rowptr[d] + atomicAdd(&cnt[d], 1);
        esrc[p] = src[e];
    }
}

// ---------------- pre-scale: hs = feats * outn ----------------
__global__ void scale_kernel(const float* __restrict__ feats, const float* __restrict__ outn,
                             float* __restrict__ hs, int n) {
    int idx = blockIdx.x * blockDim.x + threadIdx.x;   // one float4 per thread
    if (idx < n * (DD / 4)) {
        int v = idx >> 4;
        float s = outn[v];
        float4 f = ((const float4*)feats)[idx];
        f.x *= s; f.y *= s; f.z *= s; f.w *= s;
        ((float4*)hs)[idx] = f;
    }
}

// ---------------- fused per-layer: CSR gather + dual matvec + LN + relu + JK ----------------
// hs_in is the SCALED previous-layer output (h * outn). hs_in must not alias hs_out.
// Gather: lane = (stripe g = lane>>4, feat4 q = lane&15); 16 edges (4 indep float4
// loads/lane) in flight per batch -> one vmcnt round covers deg<=16 (77% of nodes).
// Masked stripes read row 0 (valid) and are zeroed via the fma multiplicand.
// NO forced waves/EU clause: (512,6) in R5 forced VGPR->40 and spilled.
__global__ __launch_bounds__(512) void gcn_kernel(
    const int* __restrict__ rowptr, const int* __restrict__ esrc,
    const float* __restrict__ inn, const float* __restrict__ rs,
    const float* __restrict__ outn,
    const float* __restrict__ hs_in,
    const float* __restrict__ Wc, const float* __restrict__ bc,
    const float* __restrict__ Wr, const float* __restrict__ br,
    const float* __restrict__ g, const float* __restrict__ bb,
    float* __restrict__ hs_out, float* __restrict__ h_final,
    int first, int n)
{
    __shared__ float sW[2 * WMAT];   // transposed: sW[j*WPAD + k] = W[k*DD + j]
    for (int idx = threadIdx.x; idx < DD * DD; idx += blockDim.x) {
        int k = idx >> 6, j = idx & 63;
        sW[j * WPAD + k]        = Wc[idx];
        sW[WMAT + j * WPAD + k] = Wr[idx];
    }
    __syncthreads();

    int lane = threadIdx.x & 63;
    int wave = threadIdx.x >> 6;
    int stride = (gridDim.x * blockDim.x) >> 6;
    int q  = lane & 15;   // float4 feature group (features 4q..4q+3)
    int gg = lane >> 4;   // edge stripe 0..3
    const float4* wcl = (const float4*)&sW[lane * WPAD];
    const float4* wrl = (const float4*)&sW[WMAT + lane * WPAD];
    float bias = bc[lane] + br[lane];
    float gl = g[lane], bbl = bb[lane];

    int v = blockIdx.x * (blockDim.x >> 6) + wave;
    // prologue: index prefetch for first node
    int start = 0, deg = 0, eidx = 0;
    if (v < n) {
        start = rowptr[v];
        deg = rowptr[v + 1] - start;
        eidx = (lane < min(deg, 64)) ? esrc[start + lane] : 0;
    }

    while (v < n) {
        // ---- prefetch next node's indices (overlaps current node's work) ----
        int vn = v + stride;
        int startN = 0, degN = 0, eidxN = 0;
        if (vn < n) {
            startN = rowptr[vn];
            degN = rowptr[vn + 1] - startN;
            eidxN = (lane < min(degN, 64)) ? esrc[startN + lane] : 0;
        }

        // ---- gather: 16 edges in flight per batch (4 indep float4 loads/lane) ----
        float4 xa4 = make_float4(0.f, 0.f, 0.f, 0.f);
        int m = min(deg, 64);
        for (int j = 0; j < m; j += 16) {
            int sv0 = __shfl(eidx, j + gg);
            int sv1 = __shfl(eidx, j + gg + 4);
            int sv2 = __shfl(eidx, j + gg + 8);
            int sv3 = __shfl(eidx, j + gg + 12);
            float4 r0 = ((const float4*)(hs_in + (size_t)sv0 * DD))[q];
            float4 r1 = ((const float4*)(hs_in + (size_t)sv1 * DD))[q];
            float4 r2 = ((const float4*)(hs_in + (size_t)sv2 * DD))[q];
            float4 r3 = ((const float4*)(hs_in + (size_t)sv3 * DD))[q];
            float k0 = (j + gg      < m) ? 1.0f : 0.0f;
            float k1 = (j + gg + 4  < m) ? 1.0f : 0.0f;
            float k2 = (j + gg + 8  < m) ? 1.0f : 0.0f;
            float k3 = (j + gg + 12 < m) ? 1.0f : 0.0f;
            xa4.x = fmaf(r0.x, k0, xa4.x); xa4.y = fmaf(r0.y, k0, xa4.y);
            xa4.z = fmaf(r0.z, k0, xa4.z); xa4.w = fmaf(r0.w, k0, xa4.w);
            xa4.x = fmaf(r1.x, k1, xa4.x); xa4.y = fmaf(r1.y, k1, xa4.y);
            xa4.z = fmaf(r1.z, k1, xa4.z); xa4.w = fmaf(r1.w, k1, xa4.w);
            xa4.x = fmaf(r2.x, k2, xa4.x); xa4.y = fmaf(r2.y, k2, xa4.y);
            xa4.z = fmaf(r2.z, k2, xa4.z); xa4.w = fmaf(r2.w, k2, xa4.w);
            xa4.x = fmaf(r3.x, k3, xa4.x); xa4.y = fmaf(r3.y, k3, xa4.y);
            xa4.z = fmaf(r3.z, k3, xa4.z); xa4.w = fmaf(r3.w, k3, xa4.w);
        }
        if (deg > 64) {  // rare slow path
            for (int base = 64; base < deg; base += 64) {
                int mm = min(64, deg - base);
                int ei = (lane < mm) ? esrc[start + base + lane] : 0;
                for (int j = 0; j < mm; j += 4) {
                    int sv = __shfl(ei, j + gg);
                    float4 r = ((const float4*)(hs_in + (size_t)sv * DD))[q];
                    float msk = (j + gg < mm) ? 1.0f : 0.0f;
                    xa4.x = fmaf(r.x, msk, xa4.x);
                    xa4.y = fmaf(r.y, msk, xa4.y);
                    xa4.z = fmaf(r.z, msk, xa4.z);
                    xa4.w = fmaf(r.w, msk, xa4.w);
                }
            }
        }
        // reduce across the 4 edge stripes (lanes 16/32 apart)
        xa4.x += __shfl_xor(xa4.x, 16); xa4.y += __shfl_xor(xa4.y, 16);
        xa4.z += __shfl_xor(xa4.z, 16); xa4.w += __shfl_xor(xa4.w, 16);
        xa4.x += __shfl_xor(xa4.x, 32); xa4.y += __shfl_xor(xa4.y, 32);
        xa4.z += __shfl_xor(xa4.z, 32); xa4.w += __shfl_xor(xa4.w, 32);

        float innv = inn[v];
        xa4.x *= innv; xa4.y *= innv; xa4.z *= innv; xa4.w *= innv;

        float rsv = rs[v];
        float4 xh4 = ((const float4*)(hs_in + (size_t)v * DD))[q];  // self row
        xh4.x *= rsv; xh4.y *= rsv; xh4.z *= rsv; xh4.w *= rsv;     // unscale

        // ---- dual matvec: feature k=4*kk+c lives in component c of lane kk ----
        float acc = bias;
        #pragma unroll
        for (int kk = 0; kk < 16; ++kk) {
            float4 wc4 = wcl[kk];
            float4 wr4 = wrl[kk];
            acc = fmaf(lane_bcast(xa4.x, kk), wc4.x, acc);
            acc = fmaf(lane_bcast(xh4.x, kk), wr4.x, acc);
            acc = fmaf(lane_bcast(xa4.y, kk), wc4.y, acc);
            acc = fmaf(lane_bcast(xh4.y, kk), wr4.y, acc);
            acc = fmaf(lane_bcast(xa4.z, kk), wc4.z, acc);
            acc = fmaf(lane_bcast(xh4.z, kk), wr4.z, acc);
            acc = fmaf(lane_bcast(xa4.w, kk), wc4.w, acc);
            acc = fmaf(lane_bcast(xh4.w, kk), wr4.w, acc);
        }

        // ---- LayerNorm across 64 lanes + relu ----
        float s = acc;
        #pragma unroll
        for (int m2 = 32; m2 >= 1; m2 >>= 1) s += __shfl_xor(s, m2);
        float mu = s * (1.0f / 64.0f);
        float c = acc - mu;
        float vs = c * c;
        #pragma unroll
        for (int m2 = 32; m2 >= 1; m2 >>= 1) vs += __shfl_xor(vs, m2);
        float var = vs * (1.0f / 64.0f);
        float y = fmaxf(c * rsqrtf(var + 1e-5f) * gl + bbl, 0.0f);

        hs_out[(size_t)v * DD + lane] = y * outn[v];   // store pre-scaled for next gather
        h_final[(size_t)v * DD + lane] = first ? y : (h_final[(size_t)v * DD + lane] + y);

        v = vn; start = startN; deg = degN; eidx = eidxN;
    }
}

// ---------------- final prediction matvec (LDS weights) ----------------
__global__ __launch_bounds__(512) void pred_kernel(
    const float* __restrict__ h_final, const float* __restrict__ W,
    const float* __restrict__ b, float* __restrict__ out, int n)
{
    __shared__ float sW[WMAT];
    for (int idx = threadIdx.x; idx < DD * DD; idx += blockDim.x) {
        int k = idx >> 6, j = idx & 63;
        sW[j * WPAD + k] = W[idx];
    }
    __syncthreads();

    int lane = threadIdx.x & 63;
    int wave = threadIdx.x >> 6;
    int wavesTotal = (gridDim.x * blockDim.x) >> 6;
    int q = lane & 15;
    const float4* wl = (const float4*)&sW[lane * WPAD];
    float bl = b[lane];

    for (int v = blockIdx.x * (blockDim.x >> 6) + wave; v < n; v += wavesTotal) {
        float4 xh4 = ((const float4*)(h_final + (size_t)v * DD))[q];
        float acc = bl;
        #pragma unroll
        for (int kk = 0; kk < 16; ++kk) {
            float4 w4 = wl[kk];
            acc = fmaf(lane_bcast(xh4.x, kk), w4.x, acc);
            acc = fmaf(lane_bcast(xh4.y, kk), w4.y, acc);
            acc = fmaf(lane_bcast(xh4.z, kk), w4.z, acc);
            acc = fmaf(lane_bcast(xh4.w, kk), w4.w, acc);
        }
        out[(size_t)v * DD + lane] = acc;
    }
}

extern "C" void kernel_launch(void* const* d_in, const int* in_sizes, int n_in,
                              void* d_out, int out_size, void* d_ws, size_t ws_size,
                              hipStream_t stream) {
    const float* feats  = (const float*)d_in[0];
    const int*   src    = (const int*)d_in[1];
    const int*   dst    = (const int*)d_in[2];
    const float* conv_W = (const float*)d_in[3];
    const float* conv_b = (const float*)d_in[4];
    const float* res_W  = (const float*)d_in[5];
    const float* res_b  = (const float*)d_in[6];
    const float* ln_g   = (const float*)d_in[7];
    const float* ln_b   = (const float*)d_in[8];
    const float* pred_W = (const float*)d_in[9];
    const float* pred_b = (const float*)d_in[10];

    int N = in_sizes[0] / DD;
    int E = in_sizes[1];
    int nb = (N + SCAN_B - 1) / SCAN_B;

    // workspace layout (~58.2 MB)
    int*   outd_i = (int*)d_ws;            // N
    int*   ind_i  = outd_i + N;            // N
    int*   cnt    = ind_i + N;             // N
    int*   rowptr = cnt + N;               // N+1
    int*   bsums  = rowptr + N + 1;        // 512
    int*   esrc   = bsums + 512;           // E
    float* outn   = (float*)(esrc + E);    // N
    float* inn    = outn + N;              // N
    float* rs     = inn + N;               // N
    float* hsA    = rs + N;                // N*DD  (scaled h ping)
    float* hfin   = hsA + (size_t)N * DD;  // N*DD
    float* hsB    = (float*)d_out;         // scaled h pong (pred overwrites last)

    hipMemsetAsync(outd_i, 0, (size_t)3 * N * sizeof(int), stream);

    hist_kernel<<<(E + 255) / 256, 256, 0, stream>>>(src, dst, outd_i, ind_i, E);
    norm_kernel<<<(N + 255) / 256, 256, 0, stream>>>(outd_i, ind_i, outn, inn, rs, N);

    scan1_kernel<<<nb, SCAN_B, 0, stream>>>(ind_i, rowptr, bsums, N);
    scan2_kernel<<<1, 512, 0, stream>>>(bsums, nb);
    scan3_kernel<<<nb, SCAN_B, 0, stream>>>(rowptr, bsums, N, E);
    fill_kernel<<<(E + 255) / 256, 256, 0, stream>>>(src, dst, rowptr, cnt, esrc, E);

    scale_kernel<<<(N * (DD / 4) + 255) / 256, 256, 0, stream>>>(feats, outn, hsA, N);

    // ping-pong (scaled): hsA -> hsB(d_out) -> hsA -> hsB(dead, pred overwrites)
    const float* ins[3]  = {hsA, hsB, hsA};
    float*       outs[3] = {hsB, hsA, hsB};
    for (int l = 0; l < 3; ++l) {
        gcn_kernel<<<768, 512, 0, stream>>>(
            rowptr, esrc, inn, rs, outn, ins[l],
            conv_W + (size_t)l * DD * DD, conv_b + (size_t)l * DD,
            res_W  + (size_t)l * DD * DD, res_b  + (size_t)l * DD,
            ln_g   + (size_t)l * DD,      ln_b   + (size_t)l * DD,
            outs[l], hfin, (l == 0) ? 1 : 0, N);
    }
    pred_kernel<<<768, 512, 0, stream>>>(hfin, pred_W, pred_b, (float*)d_out, N);
}

// Round 8
// 531.383 us; speedup vs baseline: 2.5840x; 1.3334x over previous
//
#include <hip/hip_runtime.h>
#include <hip/hip_bf16.h>

#define DD 64
#define SCAN_B 256

typedef __attribute__((ext_vector_type(8))) short short8v;  // 8 bf16 (4 VGPR) MFMA A/B frag
typedef __attribute__((ext_vector_type(4))) float f32x4;    // MFMA C/D frag

__device__ __forceinline__ unsigned pk_bf16(float a, float b) {
    __hip_bfloat162 h = __float22bfloat162_rn(make_float2(a, b));
    unsigned u; __builtin_memcpy(&u, &h, 4); return u;
}
__device__ __forceinline__ short f2bf_s(float f) {   // RNE scalar (startup only)
    union { float f; unsigned u; } x; x.f = f;
    unsigned r = x.u + 0x7fff + ((x.u >> 16) & 1);
    return (short)(r >> 16);
}

// ---------------- degree histogram (int) ----------------
__global__ void hist_kernel(const int* __restrict__ src, const int* __restrict__ dst,
                            int* __restrict__ outd, int* __restrict__ ind, int E) {
    int e = blockIdx.x * blockDim.x + threadIdx.x;
    if (e < E) {
        atomicAdd(&outd[src[e]], 1);
        atomicAdd(&ind[dst[e]], 1);
    }
}

__global__ void norm_kernel(const int* __restrict__ outd, const int* __restrict__ ind,
                            float* __restrict__ outn, float* __restrict__ inn,
                            float* __restrict__ rs, int n) {
    int i = blockIdx.x * blockDim.x + threadIdx.x;
    if (i < n) {
        float od = fmaxf((float)outd[i], 1.0f);
        outn[i] = rsqrtf(od);
        rs[i]   = sqrtf(od);
        inn[i]  = rsqrtf(fmaxf((float)ind[i], 1.0f));
    }
}

// ---------------- exclusive scan of in-degrees -> rowptr ----------------
__global__ void scan1_kernel(const int* __restrict__ in, int* __restrict__ out,
                             int* __restrict__ bsums, int n) {
    __shared__ int tmp[SCAN_B];
    int gid = blockIdx.x * SCAN_B + threadIdx.x;
    int v = (gid < n) ? in[gid] : 0;
    tmp[threadIdx.x] = v;
    __syncthreads();
    for (int off = 1; off < SCAN_B; off <<= 1) {
        int t = (threadIdx.x >= off) ? tmp[threadIdx.x - off] : 0;
        __syncthreads();
        tmp[threadIdx.x] += t;
        __syncthreads();
    }
    if (gid < n) out[gid] = tmp[threadIdx.x] - v;
    if (threadIdx.x == SCAN_B - 1) bsums[blockIdx.x] = tmp[SCAN_B - 1];
}

__global__ void scan2_kernel(int* __restrict__ bsums, int nb) {
    __shared__ int tmp[512];
    int v = (threadIdx.x < nb) ? bsums[threadIdx.x] : 0;
    tmp[threadIdx.x] = v;
    __syncthreads();
    for (int off = 1; off < 512; off <<= 1) {
        int t = (threadIdx.x >= off) ? tmp[threadIdx.x - off] : 0;
        __syncthreads();
        tmp[threadIdx.x] += t;
        __syncthreads();
    }
    if (threadIdx.x < nb) bsums[threadIdx.x] = tmp[threadIdx.x] - v;
}

__global__ void scan3_kernel(int* __restrict__ out, const int* __restrict__ bsums,
                             int n, int E) {
    int gid = blockIdx.x * SCAN_B + threadIdx.x;
    if (gid < n) out[gid] += bsums[blockIdx.x];
    if (gid == 0) out[n] = E;
}

// ---------------- CSR fill: edges grouped by dst ----------------
__global__ void fill_kernel(const int* __restrict__ src, const int* __restrict__ dst,
                            const int* __restrict__ rowptr, int* __restrict__ cnt,
                            int* __restrict__ esrc, int E) {
    int e = blockIdx.x * blockDim.x + threadIdx.x;
    if (e < E) {
        int d = dst[e];
        int p = rowptr[d] + atomicAdd(&cnt[d], 1);
        esrc[p] = src[e];
    }
}

// ---------------- pre-scale: hs = feats * outn ----------------
__global__ void scale_kernel(const float* __restrict__ feats, const float* __restrict__ outn,
                             float* __restrict__ hs, int n) {
    int idx = blockIdx.x * blockDim.x + threadIdx.x;
    if (idx < n * (DD / 4)) {
        int v = idx >> 4;
        float s = outn[v];
        float4 f = ((const float4*)feats)[idx];
        f.x *= s; f.y *= s; f.z *= s; f.w *= s;
        ((float4*)hs)[idx] = f;
    }
}

// ---------------- fused per-layer: CSR gather + MFMA dual matvec + LN + relu + JK ---------
// 16 nodes per wave-group. Gather identical to R7 (verified). Matvec via
// mfma_f32_16x16x32_bf16: D[feat_tile][node] = Wt_frag(A) x X_frag(B).
// A: m=lane&15,k=(lane>>4)*8+j ; B: n=lane&15,k=(lane>>4)*8+j ;
// D: col(node)=lane&15, row(feat)=(lane>>4)*4+reg.
__global__ __launch_bounds__(512) void gcn_kernel(
    const int* __restrict__ rowptr, const int* __restrict__ esrc,
    const float* __restrict__ inn, const float* __restrict__ rs,
    const float* __restrict__ outn,
    const float* __restrict__ hs_in,
    const float* __restrict__ Wc, const float* __restrict__ bc,
    const float* __restrict__ Wr, const float* __restrict__ br,
    const float* __restrict__ g, const float* __restrict__ bb,
    float* __restrict__ hs_out, float* __restrict__ h_final,
    int first, int n)
{
    __shared__ __align__(16) short sWf[16 * 64 * 8];  // 16 weight A-frags x 64 lanes x 8 bf16
    __shared__ __align__(16) short sXa[8][16 * 72];   // per-wave xa (16 nodes, 72-short padded rows)
    __shared__ float sEps[3 * 64];                    // bias | ln_g | ln_b

    int lane = threadIdx.x & 63;
    int wave = threadIdx.x >> 6;
    int q  = lane & 15;   // gather: feat4 chunk | mfma: node id
    int gg = lane >> 4;   // gather: edge stripe | mfma: k-quad / feat-quad

    for (int idx = threadIdx.x; idx < 64; idx += blockDim.x) {
        sEps[idx]       = bc[idx] + br[idx];
        sEps[64 + idx]  = g[idx];
        sEps[128 + idx] = bb[idx];
    }
    // weight A-frags: frag f = mat*8 + ft*2 + kc ; element j = W[kc*32+gg*8+j][ft*16+q]
    for (int f = wave * 2; f < wave * 2 + 2; ++f) {
        int mat = f >> 3, ft = (f >> 1) & 3, kc = f & 1;
        const float* Ws = mat ? Wr : Wc;
        int feat = ft * 16 + q;
        int k0 = kc * 32 + gg * 8;
        short8v fr;
        #pragma unroll
        for (int j = 0; j < 8; ++j) fr[j] = f2bf_s(Ws[(k0 + j) * DD + feat]);
        *(short8v*)&sWf[(f * 64 + lane) * 8] = fr;
    }
    __syncthreads();

    short* xrow_w = &sXa[wave][0];
    const short8v* wf = (const short8v*)sWf;
    int wgid = blockIdx.x * (blockDim.x >> 6) + wave;
    int nwav = (gridDim.x * blockDim.x) >> 6;
    int ngrp = (n + 15) >> 4;

    for (int grp = wgid; grp < ngrp; grp += nwav) {
        int vbase = grp << 4;
        int vo = vbase + q;                    // node this lane owns in mfma phase
        int vsel = min(vo, n - 1);

        // ---- residual self-rows: issued early, B-frag layout, overlap gather ----
        const float4* hrow = (const float4*)(hs_in + (size_t)vsel * DD);
        float4 xh00 = hrow[gg * 2];
        float4 xh01 = hrow[gg * 2 + 1];
        float4 xh10 = hrow[8 + gg * 2];
        float4 xh11 = hrow[8 + gg * 2 + 1];
        float rsv = rs[vsel];

        // ---- rowptr + all 16 nodes' edge indices pre-issued (MLP) ----
        int rp = rowptr[min(vbase + min(lane, 16), n)];
        int earr[16];
        #pragma unroll
        for (int i = 0; i < 16; ++i) {
            int st = __builtin_amdgcn_readlane(rp, i);
            int dg = __builtin_amdgcn_readlane(rp, i + 1) - st;
            earr[i] = (lane < min(dg, 64)) ? esrc[st + lane] : 0;
        }

        // ---- gather 16 nodes (R7-verified inner pattern) ----
        #pragma unroll
        for (int i = 0; i < 16; ++i) {
            int st = __builtin_amdgcn_readlane(rp, i);
            int dg = __builtin_amdgcn_readlane(rp, i + 1) - st;
            int ei = earr[i];
            float4 xa4 = make_float4(0.f, 0.f, 0.f, 0.f);
            int m = min(dg, 64);
            for (int j = 0; j < m; j += 16) {
                int sv0 = __shfl(ei, j + gg);
                int sv1 = __shfl(ei, j + gg + 4);
                int sv2 = __shfl(ei, j + gg + 8);
                int sv3 = __shfl(ei, j + gg + 12);
                float4 r0 = ((const float4*)(hs_in + (size_t)sv0 * DD))[q];
                float4 r1 = ((const float4*)(hs_in + (size_t)sv1 * DD))[q];
                float4 r2 = ((const float4*)(hs_in + (size_t)sv2 * DD))[q];
                float4 r3 = ((const float4*)(hs_in + (size_t)sv3 * DD))[q];
                float k0 = (j + gg      < m) ? 1.0f : 0.0f;
                float k1 = (j + gg + 4  < m) ? 1.0f : 0.0f;
                float k2 = (j + gg + 8  < m) ? 1.0f : 0.0f;
                float k3 = (j + gg + 12 < m) ? 1.0f : 0.0f;
                xa4.x = fmaf(r0.x, k0, xa4.x); xa4.y = fmaf(r0.y, k0, xa4.y);
                xa4.z = fmaf(r0.z, k0, xa4.z); xa4.w = fmaf(r0.w, k0, xa4.w);
                xa4.x = fmaf(r1.x, k1, xa4.x); xa4.y = fmaf(r1.y, k1, xa4.y);
                xa4.z = fmaf(r1.z, k1, xa4.z); xa4.w = fmaf(r1.w, k1, xa4.w);
                xa4.x = fmaf(r2.x, k2, xa4.x); xa4.y = fmaf(r2.y, k2, xa4.y);
                xa4.z = fmaf(r2.z, k2, xa4.z); xa4.w = fmaf(r2.w, k2, xa4.w);
                xa4.x = fmaf(r3.x, k3, xa4.x); xa4.y = fmaf(r3.y, k3, xa4.y);
                xa4.z = fmaf(r3.z, k3, xa4.z); xa4.w = fmaf(r3.w, k3, xa4.w);
            }
            if (dg > 64) {
                for (int base = 64; base < dg; base += 64) {
                    int mm = min(64, dg - base);
                    int e2 = (lane < mm) ? esrc[st + base + lane] : 0;
                    for (int j = 0; j < mm; j += 4) {
                        int sv = __shfl(e2, j + gg);
                        float4 r = ((const float4*)(hs_in + (size_t)sv * DD))[q];
                        float msk = (j + gg < mm) ? 1.0f : 0.0f;
                        xa4.x = fmaf(r.x, msk, xa4.x);
                        xa4.y = fmaf(r.y, msk, xa4.y);
                        xa4.z = fmaf(r.z, msk, xa4.z);
                        xa4.w = fmaf(r.w, msk, xa4.w);
                    }
                }
            }
            xa4.x += __shfl_xor(xa4.x, 16); xa4.y += __shfl_xor(xa4.y, 16);
            xa4.z += __shfl_xor(xa4.z, 16); xa4.w += __shfl_xor(xa4.w, 16);
            xa4.x += __shfl_xor(xa4.x, 32); xa4.y += __shfl_xor(xa4.y, 32);
            xa4.z += __shfl_xor(xa4.z, 32); xa4.w += __shfl_xor(xa4.w, 32);
            float innv = inn[min(vbase + i, n - 1)];
            if (gg == 0) {   // 16 lanes write the node's bf16 row (8 B each)
                int2 w2;
                w2.x = pk_bf16(xa4.x * innv, xa4.y * innv);
                w2.y = pk_bf16(xa4.z * innv, xa4.w * innv);
                *(int2*)&xrow_w[i * 72 + 4 * q] = w2;
            }
        }

        // ---- B fragments: xa from LDS (node q, k-chunk gg), xh packed from registers ----
        const short* xr = &xrow_w[q * 72];
        short8v ba0 = *(const short8v*)&xr[gg * 8];
        short8v ba1 = *(const short8v*)&xr[32 + gg * 8];
        union { short8v s; unsigned u[4]; } bh0u, bh1u;
        bh0u.u[0] = pk_bf16(xh00.x * rsv, xh00.y * rsv);
        bh0u.u[1] = pk_bf16(xh00.z * rsv, xh00.w * rsv);
        bh0u.u[2] = pk_bf16(xh01.x * rsv, xh01.y * rsv);
        bh0u.u[3] = pk_bf16(xh01.z * rsv, xh01.w * rsv);
        bh1u.u[0] = pk_bf16(xh10.x * rsv, xh10.y * rsv);
        bh1u.u[1] = pk_bf16(xh10.z * rsv, xh10.w * rsv);
        bh1u.u[2] = pk_bf16(xh11.x * rsv, xh11.y * rsv);
        bh1u.u[3] = pk_bf16(xh11.z * rsv, xh11.w * rsv);

        // ---- 16 MFMA: 4 feat-tiles x (conv kc0,kc1 + res kc0,kc1) ----
        f32x4 acc[4];
        #pragma unroll
        for (int ft = 0; ft < 4; ++ft) {
            f32x4 a = {0.f, 0.f, 0.f, 0.f};
            a = __builtin_amdgcn_mfma_f32_16x16x32_bf16(wf[(ft * 2 + 0) * 64 + lane], ba0,    a, 0, 0, 0);
            a = __builtin_amdgcn_mfma_f32_16x16x32_bf16(wf[(ft * 2 + 1) * 64 + lane], ba1,    a, 0, 0, 0);
            a = __builtin_amdgcn_mfma_f32_16x16x32_bf16(wf[(8 + ft * 2 + 0) * 64 + lane], bh0u.s, a, 0, 0, 0);
            a = __builtin_amdgcn_mfma_f32_16x16x32_bf16(wf[(8 + ft * 2 + 1) * 64 + lane], bh1u.s, a, 0, 0, 0);
            acc[ft] = a;
        }

        // ---- bias + LayerNorm (node = lane&15; its 64 feats = 4 lanes x 16 regs) ----
        #pragma unroll
        for (int ft = 0; ft < 4; ++ft) {
            float4 b4 = *(const float4*)&sEps[ft * 16 + gg * 4];
            acc[ft][0] += b4.x; acc[ft][1] += b4.y; acc[ft][2] += b4.z; acc[ft][3] += b4.w;
        }
        float s = 0.f;
        #pragma unroll
        for (int ft = 0; ft < 4; ++ft) s += acc[ft][0] + acc[ft][1] + acc[ft][2] + acc[ft][3];
        s += __shfl_xor(s, 16); s += __shfl_xor(s, 32);
        float mu = s * (1.0f / 64.0f);
        float vsum = 0.f;
        #pragma unroll
        for (int ft = 0; ft < 4; ++ft) {
            #pragma unroll
            for (int r = 0; r < 4; ++r) { float d = acc[ft][r] - mu; vsum += d * d; }
        }
        vsum += __shfl_xor(vsum, 16); vsum += __shfl_xor(vsum, 32);
        float rinv = rsqrtf(vsum * (1.0f / 64.0f) + 1e-5f);

        if (vo < n) {
            float on = outn[vo];
            #pragma unroll
            for (int ft = 0; ft < 4; ++ft) {
                float4 g4 = *(const float4*)&sEps[64 + ft * 16 + gg * 4];
                float4 c4 = *(const float4*)&sEps[128 + ft * 16 + gg * 4];
                float4 y;
                y.x = fmaxf((acc[ft][0] - mu) * rinv * g4.x + c4.x, 0.f);
                y.y = fmaxf((acc[ft][1] - mu) * rinv * g4.y + c4.y, 0.f);
                y.z = fmaxf((acc[ft][2] - mu) * rinv * g4.z + c4.z, 0.f);
                y.w = fmaxf((acc[ft][3] - mu) * rinv * g4.w + c4.w, 0.f);
                size_t off = (size_t)vo * DD + ft * 16 + gg * 4;
                float4 o = make_float4(y.x * on, y.y * on, y.z * on, y.w * on);
                *(float4*)&hs_out[off] = o;
                if (first) {
                    *(float4*)&h_final[off] = y;
                } else {
                    float4 hf = *(const float4*)&h_final[off];
                    hf.x += y.x; hf.y += y.y; hf.z += y.z; hf.w += y.w;
                    *(float4*)&h_final[off] = hf;
                }
            }
        }
    }
}

// ---------------- final prediction matvec (LDS weights, fp32) ----------------
#define WPAD 68
#define WMAT (DD * WPAD)
__device__ __forceinline__ float lane_bcast(float x, int k) {
    return __int_as_float(__builtin_amdgcn_readlane(__float_as_int(x), k));
}
__global__ __launch_bounds__(512) void pred_kernel(
    const float* __restrict__ h_final, const float* __restrict__ W,
    const float* __restrict__ b, float* __restrict__ out, int n)
{
    __shared__ float sW[WMAT];
    for (int idx = threadIdx.x; idx < DD * DD; idx += blockDim.x) {
        int k = idx >> 6, j = idx & 63;
        sW[j * WPAD + k] = W[idx];
    }
    __syncthreads();

    int lane = threadIdx.x & 63;
    int wave = threadIdx.x >> 6;
    int wavesTotal = (gridDim.x * blockDim.x) >> 6;
    int q = lane & 15;
    const float4* wl = (const float4*)&sW[lane * WPAD];
    float bl = b[lane];

    for (int v = blockIdx.x * (blockDim.x >> 6) + wave; v < n; v += wavesTotal) {
        float4 xh4 = ((const float4*)(h_final + (size_t)v * DD))[q];
        float acc = bl;
        #pragma unroll
        for (int kk = 0; kk < 16; ++kk) {
            float4 w4 = wl[kk];
            acc = fmaf(lane_bcast(xh4.x, kk), w4.x, acc);
            acc = fmaf(lane_bcast(xh4.y, kk), w4.y, acc);
            acc = fmaf(lane_bcast(xh4.z, kk), w4.z, acc);
            acc = fmaf(lane_bcast(xh4.w, kk), w4.w, acc);
        }
        out[(size_t)v * DD + lane] = acc;
    }
}

extern "C" void kernel_launch(void* const* d_in, const int* in_sizes, int n_in,
                              void* d_out, int out_size, void* d_ws, size_t ws_size,
                              hipStream_t stream) {
    const float* feats  = (const float*)d_in[0];
    const int*   src    = (const int*)d_in[1];
    const int*   dst    = (const int*)d_in[2];
    const float* conv_W = (const float*)d_in[3];
    const float* conv_b = (const float*)d_in[4];
    const float* res_W  = (const float*)d_in[5];
    const float* res_b  = (const float*)d_in[6];
    const float* ln_g   = (const float*)d_in[7];
    const float* ln_b   = (const float*)d_in[8];
    const float* pred_W = (const float*)d_in[9];
    const float* pred_b = (const float*)d_in[10];

    int N = in_sizes[0] / DD;
    int E = in_sizes[1];
    int nb = (N + SCAN_B - 1) / SCAN_B;

    // workspace layout (~58 MB)
    int*   outd_i = (int*)d_ws;            // N
    int*   ind_i  = outd_i + N;            // N
    int*   cnt    = ind_i + N;             // N
    int*   rowptr = cnt + N;               // N+1
    int*   bsums  = rowptr + N + 1;        // 512
    int*   esrc   = bsums + 512;           // E
    float* outn   = (float*)(esrc + E);    // N
    float* inn    = outn + N;              // N
    float* rs     = inn + N;               // N
    float* hsA    = (float*)(((uintptr_t)(rs + N) + 15) & ~(uintptr_t)15);  // N*DD, 16B-aligned
    float* hfin   = hsA + (size_t)N * DD;  // N*DD (16B-aligned)
    float* hsB    = (float*)d_out;         // ping-pong via d_out; pred overwrites last

    hipMemsetAsync(outd_i, 0, (size_t)3 * N * sizeof(int), stream);

    hist_kernel<<<(E + 255) / 256, 256, 0, stream>>>(src, dst, outd_i, ind_i, E);
    norm_kernel<<<(N + 255) / 256, 256, 0, stream>>>(outd_i, ind_i, outn, inn, rs, N);

    scan1_kernel<<<nb, SCAN_B, 0, stream>>>(ind_i, rowptr, bsums, N);
    scan2_kernel<<<1, 512, 0, stream>>>(bsums, nb);
    scan3_kernel<<<nb, SCAN_B, 0, stream>>>(rowptr, bsums, N, E);
    fill_kernel<<<(E + 255) / 256, 256, 0, stream>>>(src, dst, rowptr, cnt, esrc, E);

    scale_kernel<<<(N * (DD / 4) + 255) / 256, 256, 0, stream>>>(feats, outn, hsA, N);

    // ping-pong (scaled): hsA -> hsB(d_out) -> hsA -> hsB(dead, pred overwrites)
    const float* ins[3]  = {hsA, hsB, hsA};
    float*       outs[3] = {hsB, hsA, hsB};
    for (int l = 0; l < 3; ++l) {
        gcn_kernel<<<768, 512, 0, stream>>>(
            rowptr, esrc, inn, rs, outn, ins[l],
            conv_W + (size_t)l * DD * DD, conv_b + (size_t)l * DD,
            res_W  + (size_t)l * DD * DD, res_b  + (size_t)l * DD,
            ln_g   + (size_t)l * DD,      ln_b   + (size_t)l * DD,
            outs[l], hfin, (l == 0) ? 1 : 0, N);
    }
    pred_kernel<<<768, 512, 0, stream>>>(hfin, pred_W, pred_b, (float*)d_out, N);
}

// Round 9
// 437.300 us; speedup vs baseline: 3.1400x; 1.2151x over previous
//
#include <hip/hip_runtime.h>
#include <hip/hip_bf16.h>

#define DD 64
#define SCAN_B 256

typedef __attribute__((ext_vector_type(8))) short short8v;  // 8 bf16 MFMA A/B frag
typedef __attribute__((ext_vector_type(4))) float f32x4;    // MFMA C/D frag

__device__ __forceinline__ unsigned pk_bf16(float a, float b) {
    __hip_bfloat162 h = __float22bfloat162_rn(make_float2(a, b));
    unsigned u; __builtin_memcpy(&u, &h, 4); return u;
}
__device__ __forceinline__ short f2bf_s(float f) {   // RNE scalar (startup only)
    union { float f; unsigned u; } x; x.f = f;
    unsigned r = x.u + 0x7fff + ((x.u >> 16) & 1);
    return (short)(r >> 16);
}
__device__ __forceinline__ float bf_lo(unsigned u) { return __int_as_float(u << 16); }
__device__ __forceinline__ float bf_hi(unsigned u) { return __int_as_float(u & 0xffff0000u); }
__device__ __forceinline__ short8v u4_to_s8(uint4 u) {
    union { uint4 u; short8v s; } x; x.u = u; return x.s;
}

// ---------------- degree histogram (int) ----------------
__global__ void hist_kernel(const int* __restrict__ src, const int* __restrict__ dst,
                            int* __restrict__ outd, int* __restrict__ ind, int E) {
    int e = blockIdx.x * blockDim.x + threadIdx.x;
    if (e < E) {
        atomicAdd(&outd[src[e]], 1);
        atomicAdd(&ind[dst[e]], 1);
    }
}

// ---------------- scan1 + fused norm ----------------
__global__ void scan1_kernel(const int* __restrict__ ind, const int* __restrict__ outd,
                             int* __restrict__ out, int* __restrict__ bsums,
                             float* __restrict__ outn, float* __restrict__ inn,
                             float* __restrict__ rs, int n) {
    __shared__ int tmp[SCAN_B];
    int gid = blockIdx.x * SCAN_B + threadIdx.x;
    int v = (gid < n) ? ind[gid] : 0;
    if (gid < n) {
        float od = fmaxf((float)outd[gid], 1.0f);
        outn[gid] = rsqrtf(od);
        rs[gid]   = sqrtf(od);
        inn[gid]  = rsqrtf(fmaxf((float)v, 1.0f));
    }
    tmp[threadIdx.x] = v;
    __syncthreads();
    for (int off = 1; off < SCAN_B; off <<= 1) {
        int t = (threadIdx.x >= off) ? tmp[threadIdx.x - off] : 0;
        __syncthreads();
        tmp[threadIdx.x] += t;
        __syncthreads();
    }
    if (gid < n) out[gid] = tmp[threadIdx.x] - v;
    if (threadIdx.x == SCAN_B - 1) bsums[blockIdx.x] = tmp[SCAN_B - 1];
}

__global__ void scan2_kernel(int* __restrict__ bsums, int nb) {
    __shared__ int tmp[512];
    int v = (threadIdx.x < nb) ? bsums[threadIdx.x] : 0;
    tmp[threadIdx.x] = v;
    __syncthreads();
    for (int off = 1; off < 512; off <<= 1) {
        int t = (threadIdx.x >= off) ? tmp[threadIdx.x - off] : 0;
        __syncthreads();
        tmp[threadIdx.x] += t;
        __syncthreads();
    }
    if (threadIdx.x < nb) bsums[threadIdx.x] = tmp[threadIdx.x] - v;
}

__global__ void scan3_kernel(int* __restrict__ out, const int* __restrict__ bsums,
                             int n, int E) {
    int gid = blockIdx.x * SCAN_B + threadIdx.x;
    if (gid < n) out[gid] += bsums[blockIdx.x];
    if (gid == 0) out[n] = E;
}

// ---------------- CSR fill ----------------
__global__ void fill_kernel(const int* __restrict__ src, const int* __restrict__ dst,
                            const int* __restrict__ rowptr, int* __restrict__ cnt,
                            int* __restrict__ esrc, int E) {
    int e = blockIdx.x * blockDim.x + threadIdx.x;
    if (e < E) {
        int d = dst[e];
        int p = rowptr[d] + atomicAdd(&cnt[d], 1);
        esrc[p] = src[e];
    }
}

// ---------------- pre-scale: hs(bf16) = feats * outn ----------------
__global__ void scale_kernel(const float* __restrict__ feats, const float* __restrict__ outn,
                             unsigned short* __restrict__ hs, int n) {
    int idx = blockIdx.x * blockDim.x + threadIdx.x;   // one uint4 (8 feats) per thread
    if (idx < n * 8) {
        int v = idx >> 3;
        float s = outn[v];
        const float4* fp = (const float4*)feats + (size_t)idx * 2;
        float4 f0 = fp[0], f1 = fp[1];
        uint4 o;
        o.x = pk_bf16(f0.x * s, f0.y * s); o.y = pk_bf16(f0.z * s, f0.w * s);
        o.z = pk_bf16(f1.x * s, f1.y * s); o.w = pk_bf16(f1.z * s, f1.w * s);
        ((uint4*)hs)[idx] = o;
    }
}

// ---------------- fused per-layer: bf16 CSR gather + MFMA + LN + relu + JK (+pred on last) --
// hs bf16 rows (128 B). Gather: q8=lane&7 (uint4 chunk), gg8=lane>>3 (edge stripe);
// 16 edges in flight per batch. xa = RAW neighbor sum (inn/rs folded post-MFMA per node).
// MFMA layouts identical to R8 (verified): A m=lane&15,k=(lane>>4)*8+j;
// B n=lane&15 (node), same k; C/D col=node=lane&15, row=feat=(lane>>4)*4+reg.
// Last layer: h_final round-trips LDS (same-wave DS order) into 8 pred MFMAs -> d_out.
__global__ __launch_bounds__(256) void gcn_kernel(
    const int* __restrict__ rowptr, const int* __restrict__ esrc,
    const float* __restrict__ inn, const float* __restrict__ rs,
    const float* __restrict__ outn,
    const unsigned short* __restrict__ hs_in,
    const float* __restrict__ Wc, const float* __restrict__ bc,
    const float* __restrict__ Wr, const float* __restrict__ br,
    const float* __restrict__ Wp, const float* __restrict__ pb,
    const float* __restrict__ g, const float* __restrict__ bb,
    unsigned short* __restrict__ hs_out, float* __restrict__ h_final,
    float* __restrict__ pred_out,
    int first, int last, int n)
{
    __shared__ __align__(16) short sWf[24 * 64 * 8];  // 24 A-frags (Wc|Wr|Wp) x 64 lanes x 8 bf16
    __shared__ __align__(16) short sXa[4][16 * 72];   // per-wave 16-node bf16 rows (72-short pad)
    __shared__ float sEps[4 * 64];                    // bias | ln_g | ln_b | pred_b

    int lane = threadIdx.x & 63;
    int wave = threadIdx.x >> 6;        // 0..3
    int q   = lane & 15;                // mfma: node id
    int gg  = lane >> 4;                // mfma: k/feat quad
    int q8  = lane & 7;                 // gather: uint4 chunk (feats q8*8..+7)
    int gg8 = lane >> 3;                // gather: edge stripe 0..7

    for (int idx = threadIdx.x; idx < 64; idx += blockDim.x) {
        sEps[idx]       = bc[idx] + br[idx];
        sEps[64 + idx]  = g[idx];
        sEps[128 + idx] = bb[idx];
        sEps[192 + idx] = pb[idx];
    }
    // A-frags: f = mat*8 + ft*2 + kc ; elem j = W[kc*32+gg*8+j][ft*16+q]
    for (int f = wave * 6; f < wave * 6 + 6; ++f) {
        int mat = f >> 3, ft = (f >> 1) & 3, kc = f & 1;
        const float* Ws = (mat == 0) ? Wc : (mat == 1) ? Wr : Wp;
        int feat = ft * 16 + q;
        int k0 = kc * 32 + gg * 8;
        short8v fr;
        #pragma unroll
        for (int j = 0; j < 8; ++j) fr[j] = f2bf_s(Ws[(k0 + j) * DD + feat]);
        *(short8v*)&sWf[(f * 64 + lane) * 8] = fr;
    }
    __syncthreads();

    short* xrow_w = &sXa[wave][0];
    const short8v* wf = (const short8v*)sWf;
    int wgid = blockIdx.x * 4 + wave;
    int nwav = gridDim.x * 4;
    int ngrp = (n + 15) >> 4;

    for (int grp = wgid; grp < ngrp; grp += nwav) {
        int vbase = grp << 4;
        int vo = vbase + q;
        int vsel = min(vo, n - 1);

        // self row B-frags (raw bf16), issued early to overlap gather
        const uint4* hrow = (const uint4*)(hs_in + (size_t)vsel * DD);
        uint4 bh0u = hrow[gg];
        uint4 bh1u = hrow[4 + gg];
        float rsv  = rs[vsel];
        float innv = inn[vsel];

        int rp = rowptr[min(vbase + min(lane, 16), n)];
        int earr[16];
        #pragma unroll
        for (int i = 0; i < 16; ++i) {
            int st = __builtin_amdgcn_readlane(rp, i);
            int dg = __builtin_amdgcn_readlane(rp, i + 1) - st;
            earr[i] = (lane < min(dg, 64)) ? esrc[st + lane] : 0;
        }

        // ---- gather 16 nodes: raw bf16 row sums in fp32 ----
        #pragma unroll
        for (int i = 0; i < 16; ++i) {
            int st = __builtin_amdgcn_readlane(rp, i);
            int dg = __builtin_amdgcn_readlane(rp, i + 1) - st;
            int ei = earr[i];
            float a[8];
            #pragma unroll
            for (int c = 0; c < 8; ++c) a[c] = 0.0f;
            int m = min(dg, 64);
            for (int j = 0; j < m; j += 16) {
                int svA = __shfl(ei, j + gg8);
                int svB = __shfl(ei, j + 8 + gg8);
                uint4 rA = *(const uint4*)(hs_in + (size_t)svA * DD + q8 * 8);
                uint4 rB = *(const uint4*)(hs_in + (size_t)svB * DD + q8 * 8);
                float mA = (j + gg8 < m) ? 1.0f : 0.0f;
                float mB = (j + 8 + gg8 < m) ? 1.0f : 0.0f;
                a[0] = fmaf(bf_lo(rA.x), mA, a[0]); a[1] = fmaf(bf_hi(rA.x), mA, a[1]);
                a[2] = fmaf(bf_lo(rA.y), mA, a[2]); a[3] = fmaf(bf_hi(rA.y), mA, a[3]);
                a[4] = fmaf(bf_lo(rA.z), mA, a[4]); a[5] = fmaf(bf_hi(rA.z), mA, a[5]);
                a[6] = fmaf(bf_lo(rA.w), mA, a[6]); a[7] = fmaf(bf_hi(rA.w), mA, a[7]);
                a[0] = fmaf(bf_lo(rB.x), mB, a[0]); a[1] = fmaf(bf_hi(rB.x), mB, a[1]);
                a[2] = fmaf(bf_lo(rB.y), mB, a[2]); a[3] = fmaf(bf_hi(rB.y), mB, a[3]);
                a[4] = fmaf(bf_lo(rB.z), mB, a[4]); a[5] = fmaf(bf_hi(rB.z), mB, a[5]);
                a[6] = fmaf(bf_lo(rB.w), mB, a[6]); a[7] = fmaf(bf_hi(rB.w), mB, a[7]);
            }
            if (dg > 64) {
                for (int base = 64; base < dg; base += 64) {
                    int mm = min(64, dg - base);
                    int e2 = (lane < mm) ? esrc[st + base + lane] : 0;
                    for (int j = 0; j < mm; j += 8) {
                        int sv = __shfl(e2, j + gg8);
                        uint4 r = *(const uint4*)(hs_in + (size_t)sv * DD + q8 * 8);
                        float mk = (j + gg8 < mm) ? 1.0f : 0.0f;
                        a[0] = fmaf(bf_lo(r.x), mk, a[0]); a[1] = fmaf(bf_hi(r.x), mk, a[1]);
                        a[2] = fmaf(bf_lo(r.y), mk, a[2]); a[3] = fmaf(bf_hi(r.y), mk, a[3]);
                        a[4] = fmaf(bf_lo(r.z), mk, a[4]); a[5] = fmaf(bf_hi(r.z), mk, a[5]);
                        a[6] = fmaf(bf_lo(r.w), mk, a[6]); a[7] = fmaf(bf_hi(r.w), mk, a[7]);
                    }
                }
            }
            #pragma unroll
            for (int lv = 8; lv <= 32; lv <<= 1) {
                #pragma unroll
                for (int c = 0; c < 8; ++c) a[c] += __shfl_xor(a[c], lv);
            }
            if (gg8 == 0) {   // 8 lanes write the node's bf16 row (16 B each)
                uint4 w4;
                w4.x = pk_bf16(a[0], a[1]); w4.y = pk_bf16(a[2], a[3]);
                w4.z = pk_bf16(a[4], a[5]); w4.w = pk_bf16(a[6], a[7]);
                *(uint4*)&xrow_w[i * 72 + q8 * 8] = w4;
            }
        }

        // ---- B-frags + 16 MFMA (separate conv/res accumulators) ----
        const short* xr = &xrow_w[q * 72];
        short8v ba0 = *(const short8v*)&xr[gg * 8];
        short8v ba1 = *(const short8v*)&xr[32 + gg * 8];
        short8v sh0 = u4_to_s8(bh0u);
        short8v sh1 = u4_to_s8(bh1u);

        f32x4 accC[4], accR[4];
        #pragma unroll
        for (int ft = 0; ft < 4; ++ft) {
            f32x4 c = {0.f, 0.f, 0.f, 0.f};
            c = __builtin_amdgcn_mfma_f32_16x16x32_bf16(wf[(ft * 2 + 0) * 64 + lane], ba0, c, 0, 0, 0);
            c = __builtin_amdgcn_mfma_f32_16x16x32_bf16(wf[(ft * 2 + 1) * 64 + lane], ba1, c, 0, 0, 0);
            accC[ft] = c;
            f32x4 r = {0.f, 0.f, 0.f, 0.f};
            r = __builtin_amdgcn_mfma_f32_16x16x32_bf16(wf[(8 + ft * 2 + 0) * 64 + lane], sh0, r, 0, 0, 0);
            r = __builtin_amdgcn_mfma_f32_16x16x32_bf16(wf[(8 + ft * 2 + 1) * 64 + lane], sh1, r, 0, 0, 0);
            accR[ft] = r;
        }

        // ---- combine (inn*conv + rs*res + bias) + LayerNorm + relu ----
        f32x4 ac[4];
        #pragma unroll
        for (int ft = 0; ft < 4; ++ft) {
            float4 b4 = *(const float4*)&sEps[ft * 16 + gg * 4];
            ac[ft][0] = fmaf(innv, accC[ft][0], fmaf(rsv, accR[ft][0], b4.x));
            ac[ft][1] = fmaf(innv, accC[ft][1], fmaf(rsv, accR[ft][1], b4.y));
            ac[ft][2] = fmaf(innv, accC[ft][2], fmaf(rsv, accR[ft][2], b4.z));
            ac[ft][3] = fmaf(innv, accC[ft][3], fmaf(rsv, accR[ft][3], b4.w));
        }
        float s = 0.f;
        #pragma unroll
        for (int ft = 0; ft < 4; ++ft) s += ac[ft][0] + ac[ft][1] + ac[ft][2] + ac[ft][3];
        s += __shfl_xor(s, 16); s += __shfl_xor(s, 32);
        float mu = s * (1.0f / 64.0f);
        float vsum = 0.f;
        #pragma unroll
        for (int ft = 0; ft < 4; ++ft) {
            #pragma unroll
            for (int r = 0; r < 4; ++r) { float d = ac[ft][r] - mu; vsum += d * d; }
        }
        vsum += __shfl_xor(vsum, 16); vsum += __shfl_xor(vsum, 32);
        float rinv = rsqrtf(vsum * (1.0f / 64.0f) + 1e-5f);

        float4 yv[4];
        #pragma unroll
        for (int ft = 0; ft < 4; ++ft) {
            float4 g4 = *(const float4*)&sEps[64 + ft * 16 + gg * 4];
            float4 c4 = *(const float4*)&sEps[128 + ft * 16 + gg * 4];
            yv[ft].x = fmaxf((ac[ft][0] - mu) * rinv * g4.x + c4.x, 0.f);
            yv[ft].y = fmaxf((ac[ft][1] - mu) * rinv * g4.y + c4.y, 0.f);
            yv[ft].z = fmaxf((ac[ft][2] - mu) * rinv * g4.z + c4.z, 0.f);
            yv[ft].w = fmaxf((ac[ft][3] - mu) * rinv * g4.w + c4.w, 0.f);
        }

        if (!last) {
            if (vo < n) {
                float on = outn[vo];
                #pragma unroll
                for (int ft = 0; ft < 4; ++ft) {
                    size_t off = (size_t)vo * DD + ft * 16 + gg * 4;
                    uint2 p;
                    p.x = pk_bf16(yv[ft].x * on, yv[ft].y * on);
                    p.y = pk_bf16(yv[ft].z * on, yv[ft].w * on);
                    *(uint2*)&hs_out[off] = p;
                    if (first) {
                        *(float4*)&h_final[off] = yv[ft];
                    } else {
                        float4 hf = *(const float4*)&h_final[off];
                        hf.x += yv[ft].x; hf.y += yv[ft].y;
                        hf.z += yv[ft].z; hf.w += yv[ft].w;
                        *(float4*)&h_final[off] = hf;
                    }
                }
            }
        } else {
            // fused prediction: hf = h_final + y -> LDS (bf16) -> B-frags -> 8 MFMA -> d_out
            #pragma unroll
            for (int ft = 0; ft < 4; ++ft) {
                float4 hf = make_float4(0.f, 0.f, 0.f, 0.f);
                if (vo < n) {
                    float4 old = *(const float4*)&h_final[(size_t)vo * DD + ft * 16 + gg * 4];
                    hf.x = old.x + yv[ft].x; hf.y = old.y + yv[ft].y;
                    hf.z = old.z + yv[ft].z; hf.w = old.w + yv[ft].w;
                }
                uint2 p;
                p.x = pk_bf16(hf.x, hf.y);
                p.y = pk_bf16(hf.z, hf.w);
                *(uint2*)&xrow_w[q * 72 + ft * 16 + gg * 4] = p;   // same-wave DS, in order
            }
            short8v bp0 = *(const short8v*)&xr[gg * 8];
            short8v bp1 = *(const short8v*)&xr[32 + gg * 8];
            #pragma unroll
            for (int ft = 0; ft < 4; ++ft) {
                f32x4 p = {0.f, 0.f, 0.f, 0.f};
                p = __builtin_amdgcn_mfma_f32_16x16x32_bf16(wf[(16 + ft * 2 + 0) * 64 + lane], bp0, p, 0, 0, 0);
                p = __builtin_amdgcn_mfma_f32_16x16x32_bf16(wf[(16 + ft * 2 + 1) * 64 + lane], bp1, p, 0, 0, 0);
                if (vo < n) {
                    float4 b4 = *(const float4*)&sEps[192 + ft * 16 + gg * 4];
                    float4 o = make_float4(p[0] + b4.x, p[1] + b4.y, p[2] + b4.z, p[3] + b4.w);
                    *(float4*)&pred_out[(size_t)vo * DD + ft * 16 + gg * 4] = o;
                }
            }
        }
    }
}

extern "C" void kernel_launch(void* const* d_in, const int* in_sizes, int n_in,
                              void* d_out, int out_size, void* d_ws, size_t ws_size,
                              hipStream_t stream) {
    const float* feats  = (const float*)d_in[0];
    const int*   src    = (const int*)d_in[1];
    const int*   dst    = (const int*)d_in[2];
    const float* conv_W = (const float*)d_in[3];
    const float* conv_b = (const float*)d_in[4];
    const float* res_W  = (const float*)d_in[5];
    const float* res_b  = (const float*)d_in[6];
    const float* ln_g   = (const float*)d_in[7];
    const float* ln_b   = (const float*)d_in[8];
    const float* pred_W = (const float*)d_in[9];
    const float* pred_b = (const float*)d_in[10];

    int N = in_sizes[0] / DD;
    int E = in_sizes[1];
    int nb = (N + SCAN_B - 1) / SCAN_B;

    // workspace layout (~58 MB)
    int*   outd_i = (int*)d_ws;             // N
    int*   ind_i  = outd_i + N;             // N
    int*   cnt    = ind_i + N;              // N
    int*   rowptr = cnt + N;                // N+1
    int*   bsums  = rowptr + N + 1;         // 512
    int*   esrc   = bsums + 512;            // E
    float* outn   = (float*)(esrc + E);     // N
    float* inn    = outn + N;               // N
    float* rs     = inn + N;                // N
    float* base   = (float*)(((uintptr_t)(rs + N) + 15) & ~(uintptr_t)15);
    unsigned short* hsA = (unsigned short*)base;                 // N*64 bf16
    unsigned short* hsB = (unsigned short*)(base + (size_t)N * 32);  // N*64 bf16
    float* hfin  = base + (size_t)N * 64;   // N*64 fp32

    hipMemsetAsync(outd_i, 0, (size_t)3 * N * sizeof(int), stream);

    hist_kernel<<<(E + 255) / 256, 256, 0, stream>>>(src, dst, outd_i, ind_i, E);
    scan1_kernel<<<nb, SCAN_B, 0, stream>>>(ind_i, outd_i, rowptr, bsums, outn, inn, rs, N);
    scan2_kernel<<<1, 512, 0, stream>>>(bsums, nb);
    scan3_kernel<<<nb, SCAN_B, 0, stream>>>(rowptr, bsums, N, E);
    fill_kernel<<<(E + 255) / 256, 256, 0, stream>>>(src, dst, rowptr, cnt, esrc, E);
    scale_kernel<<<(N * 8 + 255) / 256, 256, 0, stream>>>(feats, outn, hsA, N);

    // L1: hsA->hsB ; L2: hsB->hsA ; L3: hsA->(pred d_out), hs_out unused
    const unsigned short* ins[3]  = {hsA, hsB, hsA};
    unsigned short*       outs[3] = {hsB, hsA, hsB};
    for (int l = 0; l < 3; ++l) {
        gcn_kernel<<<1024, 256, 0, stream>>>(
            rowptr, esrc, inn, rs, outn, ins[l],
            conv_W + (size_t)l * DD * DD, conv_b + (size_t)l * DD,
            res_W  + (size_t)l * DD * DD, res_b  + (size_t)l * DD,
            pred_W, pred_b,
            ln_g   + (size_t)l * DD,      ln_b   + (size_t)l * DD,
            outs[l], hfin, (float*)d_out,
            (l == 0) ? 1 : 0, (l == 2) ? 1 : 0, N);
    }
}

// Round 10
// 379.501 us; speedup vs baseline: 3.6182x; 1.1523x over previous
//
#include <hip/hip_runtime.h>
#include <hip/hip_bf16.h>

#define DD 64
#define SCAN_B 256

typedef __attribute__((ext_vector_type(8))) short short8v;  // 8 bf16 MFMA A/B frag
typedef __attribute__((ext_vector_type(4))) float f32x4;    // MFMA C/D frag

__device__ __forceinline__ unsigned pk_bf16(float a, float b) {
    __hip_bfloat162 h = __float22bfloat162_rn(make_float2(a, b));
    unsigned u; __builtin_memcpy(&u, &h, 4); return u;
}
__device__ __forceinline__ short f2bf_s(float f) {   // RNE scalar (startup only)
    union { float f; unsigned u; } x; x.f = f;
    unsigned r = x.u + 0x7fff + ((x.u >> 16) & 1);
    return (short)(r >> 16);
}
__device__ __forceinline__ float bf_lo(unsigned u) { return __int_as_float(u << 16); }
__device__ __forceinline__ float bf_hi(unsigned u) { return __int_as_float(u & 0xffff0000u); }
__device__ __forceinline__ short8v u4_to_s8(uint4 u) {
    union { uint4 u; short8v s; } x; x.u = u; return x.s;
}

// ---------------- degree histogram (int) ----------------
__global__ void hist_kernel(const int* __restrict__ src, const int* __restrict__ dst,
                            int* __restrict__ outd, int* __restrict__ ind, int E) {
    int e = blockIdx.x * blockDim.x + threadIdx.x;
    if (e < E) {
        atomicAdd(&outd[src[e]], 1);
        atomicAdd(&ind[dst[e]], 1);
    }
}

// ---------------- scan1 + fused norm ----------------
__global__ void scan1_kernel(const int* __restrict__ ind, const int* __restrict__ outd,
                             int* __restrict__ out, int* __restrict__ bsums,
                             float* __restrict__ outn, float* __restrict__ inn,
                             float* __restrict__ rs, int n) {
    __shared__ int tmp[SCAN_B];
    int gid = blockIdx.x * SCAN_B + threadIdx.x;
    int v = (gid < n) ? ind[gid] : 0;
    if (gid < n) {
        float od = fmaxf((float)outd[gid], 1.0f);
        outn[gid] = rsqrtf(od);
        rs[gid]   = sqrtf(od);
        inn[gid]  = rsqrtf(fmaxf((float)v, 1.0f));
    }
    tmp[threadIdx.x] = v;
    __syncthreads();
    for (int off = 1; off < SCAN_B; off <<= 1) {
        int t = (threadIdx.x >= off) ? tmp[threadIdx.x - off] : 0;
        __syncthreads();
        tmp[threadIdx.x] += t;
        __syncthreads();
    }
    if (gid < n) out[gid] = tmp[threadIdx.x] - v;
    if (threadIdx.x == SCAN_B - 1) bsums[blockIdx.x] = tmp[SCAN_B - 1];
}

__global__ void scan2_kernel(int* __restrict__ bsums, int nb) {
    __shared__ int tmp[512];
    int v = (threadIdx.x < nb) ? bsums[threadIdx.x] : 0;
    tmp[threadIdx.x] = v;
    __syncthreads();
    for (int off = 1; off < 512; off <<= 1) {
        int t = (threadIdx.x >= off) ? tmp[threadIdx.x - off] : 0;
        __syncthreads();
        tmp[threadIdx.x] += t;
        __syncthreads();
    }
    if (threadIdx.x < nb) bsums[threadIdx.x] = tmp[threadIdx.x] - v;
}

__global__ void scan3_kernel(int* __restrict__ out, const int* __restrict__ bsums,
                             int n, int E) {
    int gid = blockIdx.x * SCAN_B + threadIdx.x;
    if (gid < n) out[gid] += bsums[blockIdx.x];
    if (gid == 0) out[n] = E;
}

// ---------------- CSR fill ----------------
__global__ void fill_kernel(const int* __restrict__ src, const int* __restrict__ dst,
                            const int* __restrict__ rowptr, int* __restrict__ cnt,
                            int* __restrict__ esrc, int E) {
    int e = blockIdx.x * blockDim.x + threadIdx.x;
    if (e < E) {
        int d = dst[e];
        int p = rowptr[d] + atomicAdd(&cnt[d], 1);
        esrc[p] = src[e];
    }
}

// ---------------- pre-scale: hs(bf16) = feats * outn ----------------
__global__ void scale_kernel(const float* __restrict__ feats, const float* __restrict__ outn,
                             unsigned short* __restrict__ hs, int n) {
    int idx = blockIdx.x * blockDim.x + threadIdx.x;   // one uint4 (8 feats) per thread
    if (idx < n * 8) {
        int v = idx >> 3;
        float s = outn[v];
        const float4* fp = (const float4*)feats + (size_t)idx * 2;
        float4 f0 = fp[0], f1 = fp[1];
        uint4 o;
        o.x = pk_bf16(f0.x * s, f0.y * s); o.y = pk_bf16(f0.z * s, f0.w * s);
        o.z = pk_bf16(f1.x * s, f1.y * s); o.w = pk_bf16(f1.z * s, f1.w * s);
        ((uint4*)hs)[idx] = o;
    }
}

// ---------------- fused per-layer: bf16 CSR gather + MFMA + LN + relu + JK (+pred on last) --
// Gather (R10 redesign for MLP): lane = (node o=lane>>3, chunk q8=lane&7). Each lane
// privately sums its node's 16B chunk over all edges — NO cross-lane reduce. 4-deep
// pipelined edge loop (4 idx prefetch + 4 independent 1KB row loads in flight).
// Two 8-node halves per 16-node MFMA group. Masked lanes load row 0 * 0.0f.
// MFMA layouts identical to R8/R9 (verified). Last layer fuses pred via LDS round-trip.
__global__ __launch_bounds__(256) void gcn_kernel(
    const int* __restrict__ rowptr, const int* __restrict__ esrc,
    const float* __restrict__ inn, const float* __restrict__ rs,
    const float* __restrict__ outn,
    const unsigned short* __restrict__ hs_in,
    const float* __restrict__ Wc, const float* __restrict__ bc,
    const float* __restrict__ Wr, const float* __restrict__ br,
    const float* __restrict__ Wp, const float* __restrict__ pb,
    const float* __restrict__ g, const float* __restrict__ bb,
    unsigned short* __restrict__ hs_out, float* __restrict__ h_final,
    float* __restrict__ pred_out,
    int first, int last, int n)
{
    __shared__ __align__(16) short sWf[24 * 64 * 8];  // 24 A-frags (Wc|Wr|Wp) x 64 lanes x 8 bf16
    __shared__ __align__(16) short sXa[4][16 * 72];   // per-wave 16-node bf16 rows (72-short pad)
    __shared__ float sEps[4 * 64];                    // bias | ln_g | ln_b | pred_b

    int lane = threadIdx.x & 63;
    int wave = threadIdx.x >> 6;        // 0..3
    int q   = lane & 15;                // mfma: node id
    int gg  = lane >> 4;                // mfma: k/feat quad
    int q8  = lane & 7;                 // gather: 16B chunk (feats q8*8..+7)
    int o8  = lane >> 3;                // gather: node-in-half 0..7

    for (int idx = threadIdx.x; idx < 64; idx += blockDim.x) {
        sEps[idx]       = bc[idx] + br[idx];
        sEps[64 + idx]  = g[idx];
        sEps[128 + idx] = bb[idx];
        sEps[192 + idx] = pb[idx];
    }
    // A-frags: f = mat*8 + ft*2 + kc ; elem j = W[kc*32+gg*8+j][ft*16+q]
    for (int f = wave * 6; f < wave * 6 + 6; ++f) {
        int mat = f >> 3, ft = (f >> 1) & 3, kc = f & 1;
        const float* Ws = (mat == 0) ? Wc : (mat == 1) ? Wr : Wp;
        int feat = ft * 16 + q;
        int k0 = kc * 32 + gg * 8;
        short8v fr;
        #pragma unroll
        for (int j = 0; j < 8; ++j) fr[j] = f2bf_s(Ws[(k0 + j) * DD + feat]);
        *(short8v*)&sWf[(f * 64 + lane) * 8] = fr;
    }
    __syncthreads();

    short* xrow_w = &sXa[wave][0];
    const short8v* wf = (const short8v*)sWf;
    int wgid = blockIdx.x * 4 + wave;
    int nwav = gridDim.x * 4;
    int ngrp = (n + 15) >> 4;

    for (int grp = wgid; grp < ngrp; grp += nwav) {
        int vbase = grp << 4;
        int vo = vbase + q;
        int vsel = min(vo, n - 1);

        // self row B-frags (raw bf16), issued early to overlap gather
        const uint4* hrow = (const uint4*)(hs_in + (size_t)vsel * DD);
        uint4 bh0u = hrow[gg];
        uint4 bh1u = hrow[4 + gg];
        float rsv  = rs[vsel];
        float innv = inn[vsel];

        // rowptr for the 16 nodes; per-lane start/deg for both halves
        int rp = rowptr[min(vbase + min(lane, 16), n)];
        int stA = __shfl(rp, o8);     int dgA = __shfl(rp, o8 + 1) - stA;
        int stB = __shfl(rp, o8 + 8); int dgB = __shfl(rp, o8 + 9) - stB;

        #pragma unroll
        for (int hh = 0; hh < 2; ++hh) {
            int st = hh ? stB : stA;
            int dg = hh ? dgB : dgA;
            // wave-uniform max degree over this half's 8 nodes
            int mdg = dg;
            mdg = max(mdg, __shfl_xor(mdg, 8));
            mdg = max(mdg, __shfl_xor(mdg, 16));
            mdg = max(mdg, __shfl_xor(mdg, 32));

            float a[8];
            #pragma unroll
            for (int c = 0; c < 8; ++c) a[c] = 0.0f;

            int id0 = (0 < dg) ? esrc[st + 0] : 0;  float m0 = (0 < dg) ? 1.f : 0.f;
            int id1 = (1 < dg) ? esrc[st + 1] : 0;  float m1 = (1 < dg) ? 1.f : 0.f;
            int id2 = (2 < dg) ? esrc[st + 2] : 0;  float m2 = (2 < dg) ? 1.f : 0.f;
            int id3 = (3 < dg) ? esrc[st + 3] : 0;  float m3 = (3 < dg) ? 1.f : 0.f;

            for (int t = 0; t < mdg; t += 4) {
                // 4 independent 16B row-chunk loads (wave: 4 x 1KB coalesced)
                uint4 r0 = *(const uint4*)(hs_in + (size_t)id0 * DD + q8 * 8);
                uint4 r1 = *(const uint4*)(hs_in + (size_t)id1 * DD + q8 * 8);
                uint4 r2 = *(const uint4*)(hs_in + (size_t)id2 * DD + q8 * 8);
                uint4 r3 = *(const uint4*)(hs_in + (size_t)id3 * DD + q8 * 8);
                float c0 = m0, c1 = m1, c2 = m2, c3 = m3;
                // prefetch next 4 edge indices (overlap row loads)
                int t4 = t + 4;
                id0 = (t4 + 0 < dg) ? esrc[st + t4 + 0] : 0;  m0 = (t4 + 0 < dg) ? 1.f : 0.f;
                id1 = (t4 + 1 < dg) ? esrc[st + t4 + 1] : 0;  m1 = (t4 + 1 < dg) ? 1.f : 0.f;
                id2 = (t4 + 2 < dg) ? esrc[st + t4 + 2] : 0;  m2 = (t4 + 2 < dg) ? 1.f : 0.f;
                id3 = (t4 + 3 < dg) ? esrc[st + t4 + 3] : 0;  m3 = (t4 + 3 < dg) ? 1.f : 0.f;
                // accumulate
                a[0] = fmaf(bf_lo(r0.x), c0, a[0]); a[1] = fmaf(bf_hi(r0.x), c0, a[1]);
                a[2] = fmaf(bf_lo(r0.y), c0, a[2]); a[3] = fmaf(bf_hi(r0.y), c0, a[3]);
                a[4] = fmaf(bf_lo(r0.z), c0, a[4]); a[5] = fmaf(bf_hi(r0.z), c0, a[5]);
                a[6] = fmaf(bf_lo(r0.w), c0, a[6]); a[7] = fmaf(bf_hi(r0.w), c0, a[7]);
                a[0] = fmaf(bf_lo(r1.x), c1, a[0]); a[1] = fmaf(bf_hi(r1.x), c1, a[1]);
                a[2] = fmaf(bf_lo(r1.y), c1, a[2]); a[3] = fmaf(bf_hi(r1.y), c1, a[3]);
                a[4] = fmaf(bf_lo(r1.z), c1, a[4]); a[5] = fmaf(bf_hi(r1.z), c1, a[5]);
                a[6] = fmaf(bf_lo(r1.w), c1, a[6]); a[7] = fmaf(bf_hi(r1.w), c1, a[7]);
                a[0] = fmaf(bf_lo(r2.x), c2, a[0]); a[1] = fmaf(bf_hi(r2.x), c2, a[1]);
                a[2] = fmaf(bf_lo(r2.y), c2, a[2]); a[3] = fmaf(bf_hi(r2.y), c2, a[3]);
                a[4] = fmaf(bf_lo(r2.z), c2, a[4]); a[5] = fmaf(bf_hi(r2.z), c2, a[5]);
                a[6] = fmaf(bf_lo(r2.w), c2, a[6]); a[7] = fmaf(bf_hi(r2.w), c2, a[7]);
                a[0] = fmaf(bf_lo(r3.x), c3, a[0]); a[1] = fmaf(bf_hi(r3.x), c3, a[1]);
                a[2] = fmaf(bf_lo(r3.y), c3, a[2]); a[3] = fmaf(bf_hi(r3.y), c3, a[3]);
                a[4] = fmaf(bf_lo(r3.z), c3, a[4]); a[5] = fmaf(bf_hi(r3.z), c3, a[5]);
                a[6] = fmaf(bf_lo(r3.w), c3, a[6]); a[7] = fmaf(bf_hi(r3.w), c3, a[7]);
            }

            // lane holds its node-chunk's final raw sums; pack + one LDS write
            uint4 w4;
            w4.x = pk_bf16(a[0], a[1]); w4.y = pk_bf16(a[2], a[3]);
            w4.z = pk_bf16(a[4], a[5]); w4.w = pk_bf16(a[6], a[7]);
            *(uint4*)&xrow_w[(hh * 8 + o8) * 72 + q8 * 8] = w4;
        }

        // ---- B-frags + 16 MFMA (separate conv/res accumulators) ----
        const short* xr = &xrow_w[q * 72];
        short8v ba0 = *(const short8v*)&xr[gg * 8];
        short8v ba1 = *(const short8v*)&xr[32 + gg * 8];
        short8v sh0 = u4_to_s8(bh0u);
        short8v sh1 = u4_to_s8(bh1u);

        f32x4 accC[4], accR[4];
        #pragma unroll
        for (int ft = 0; ft < 4; ++ft) {
            f32x4 c = {0.f, 0.f, 0.f, 0.f};
            c = __builtin_amdgcn_mfma_f32_16x16x32_bf16(wf[(ft * 2 + 0) * 64 + lane], ba0, c, 0, 0, 0);
            c = __builtin_amdgcn_mfma_f32_16x16x32_bf16(wf[(ft * 2 + 1) * 64 + lane], ba1, c, 0, 0, 0);
            accC[ft] = c;
            f32x4 r = {0.f, 0.f, 0.f, 0.f};
            r = __builtin_amdgcn_mfma_f32_16x16x32_bf16(wf[(8 + ft * 2 + 0) * 64 + lane], sh0, r, 0, 0, 0);
            r = __builtin_amdgcn_mfma_f32_16x16x32_bf16(wf[(8 + ft * 2 + 1) * 64 + lane], sh1, r, 0, 0, 0);
            accR[ft] = r;
        }

        // ---- combine (inn*conv + rs*res + bias) + LayerNorm + relu ----
        f32x4 ac[4];
        #pragma unroll
        for (int ft = 0; ft < 4; ++ft) {
            float4 b4 = *(const float4*)&sEps[ft * 16 + gg * 4];
            ac[ft][0] = fmaf(innv, accC[ft][0], fmaf(rsv, accR[ft][0], b4.x));
            ac[ft][1] = fmaf(innv, accC[ft][1], fmaf(rsv, accR[ft][1], b4.y));
            ac[ft][2] = fmaf(innv, accC[ft][2], fmaf(rsv, accR[ft][2], b4.z));
            ac[ft][3] = fmaf(innv, accC[ft][3], fmaf(rsv, accR[ft][3], b4.w));
        }
        float s = 0.f;
        #pragma unroll
        for (int ft = 0; ft < 4; ++ft) s += ac[ft][0] + ac[ft][1] + ac[ft][2] + ac[ft][3];
        s += __shfl_xor(s, 16); s += __shfl_xor(s, 32);
        float mu = s * (1.0f / 64.0f);
        float vsum = 0.f;
        #pragma unroll
        for (int ft = 0; ft < 4; ++ft) {
            #pragma unroll
            for (int r = 0; r < 4; ++r) { float d = ac[ft][r] - mu; vsum += d * d; }
        }
        vsum += __shfl_xor(vsum, 16); vsum += __shfl_xor(vsum, 32);
        float rinv = rsqrtf(vsum * (1.0f / 64.0f) + 1e-5f);

        float4 yv[4];
        #pragma unroll
        for (int ft = 0; ft < 4; ++ft) {
            float4 g4 = *(const float4*)&sEps[64 + ft * 16 + gg * 4];
            float4 c4 = *(const float4*)&sEps[128 + ft * 16 + gg * 4];
            yv[ft].x = fmaxf((ac[ft][0] - mu) * rinv * g4.x + c4.x, 0.f);
            yv[ft].y = fmaxf((ac[ft][1] - mu) * rinv * g4.y + c4.y, 0.f);
            yv[ft].z = fmaxf((ac[ft][2] - mu) * rinv * g4.z + c4.z, 0.f);
            yv[ft].w = fmaxf((ac[ft][3] - mu) * rinv * g4.w + c4.w, 0.f);
        }

        if (!last) {
            if (vo < n) {
                float on = outn[vo];
                #pragma unroll
                for (int ft = 0; ft < 4; ++ft) {
                    size_t off = (size_t)vo * DD + ft * 16 + gg * 4;
                    uint2 p;
                    p.x = pk_bf16(yv[ft].x * on, yv[ft].y * on);
                    p.y = pk_bf16(yv[ft].z * on, yv[ft].w * on);
                    *(uint2*)&hs_out[off] = p;
                    if (first) {
                        *(float4*)&h_final[off] = yv[ft];
                    } else {
                        float4 hf = *(const float4*)&h_final[off];
                        hf.x += yv[ft].x; hf.y += yv[ft].y;
                        hf.z += yv[ft].z; hf.w += yv[ft].w;
                        *(float4*)&h_final[off] = hf;
                    }
                }
            }
        } else {
            // fused prediction: hf = h_final + y -> LDS (bf16) -> B-frags -> 8 MFMA -> d_out
            #pragma unroll
            for (int ft = 0; ft < 4; ++ft) {
                float4 hf = make_float4(0.f, 0.f, 0.f, 0.f);
                if (vo < n) {
                    float4 old = *(const float4*)&h_final[(size_t)vo * DD + ft * 16 + gg * 4];
                    hf.x = old.x + yv[ft].x; hf.y = old.y + yv[ft].y;
                    hf.z = old.z + yv[ft].z; hf.w = old.w + yv[ft].w;
                }
                uint2 p;
                p.x = pk_bf16(hf.x, hf.y);
                p.y = pk_bf16(hf.z, hf.w);
                *(uint2*)&xrow_w[q * 72 + ft * 16 + gg * 4] = p;   // same-wave DS, in order
            }
            short8v bp0 = *(const short8v*)&xr[gg * 8];
            short8v bp1 = *(const short8v*)&xr[32 + gg * 8];
            #pragma unroll
            for (int ft = 0; ft < 4; ++ft) {
                f32x4 p = {0.f, 0.f, 0.f, 0.f};
                p = __builtin_amdgcn_mfma_f32_16x16x32_bf16(wf[(16 + ft * 2 + 0) * 64 + lane], bp0, p, 0, 0, 0);
                p = __builtin_amdgcn_mfma_f32_16x16x32_bf16(wf[(16 + ft * 2 + 1) * 64 + lane], bp1, p, 0, 0, 0);
                if (vo < n) {
                    float4 b4 = *(const float4*)&sEps[192 + ft * 16 + gg * 4];
                    float4 o = make_float4(p[0] + b4.x, p[1] + b4.y, p[2] + b4.z, p[3] + b4.w);
                    *(float4*)&pred_out[(size_t)vo * DD + ft * 16 + gg * 4] = o;
                }
            }
        }
    }
}

extern "C" void kernel_launch(void* const* d_in, const int* in_sizes, int n_in,
                              void* d_out, int out_size, void* d_ws, size_t ws_size,
                              hipStream_t stream) {
    const float* feats  = (const float*)d_in[0];
    const int*   src    = (const int*)d_in[1];
    const int*   dst    = (const int*)d_in[2];
    const float* conv_W = (const float*)d_in[3];
    const float* conv_b = (const float*)d_in[4];
    const float* res_W  = (const float*)d_in[5];
    const float* res_b  = (const float*)d_in[6];
    const float* ln_g   = (const float*)d_in[7];
    const float* ln_b   = (const float*)d_in[8];
    const float* pred_W = (const float*)d_in[9];
    const float* pred_b = (const float*)d_in[10];

    int N = in_sizes[0] / DD;
    int E = in_sizes[1];
    int nb = (N + SCAN_B - 1) / SCAN_B;

    // workspace layout (~58 MB)
    int*   outd_i = (int*)d_ws;             // N
    int*   ind_i  = outd_i + N;             // N
    int*   cnt    = ind_i + N;              // N
    int*   rowptr = cnt + N;                // N+1
    int*   bsums  = rowptr + N + 1;         // 512
    int*   esrc   = bsums + 512;            // E
    float* outn   = (float*)(esrc + E);     // N
    float* inn    = outn + N;               // N
    float* rs     = inn + N;                // N
    float* base   = (float*)(((uintptr_t)(rs + N) + 15) & ~(uintptr_t)15);
    unsigned short* hsA = (unsigned short*)base;                 // N*64 bf16
    unsigned short* hsB = (unsigned short*)(base + (size_t)N * 32);  // N*64 bf16
    float* hfin  = base + (size_t)N * 64;   // N*64 fp32

    hipMemsetAsync(outd_i, 0, (size_t)3 * N * sizeof(int), stream);

    hist_kernel<<<(E + 255) / 256, 256, 0, stream>>>(src, dst, outd_i, ind_i, E);
    scan1_kernel<<<nb, SCAN_B, 0, stream>>>(ind_i, outd_i, rowptr, bsums, outn, inn, rs, N);
    scan2_kernel<<<1, 512, 0, stream>>>(bsums, nb);
    scan3_kernel<<<nb, SCAN_B, 0, stream>>>(rowptr, bsums, N, E);
    fill_kernel<<<(E + 255) / 256, 256, 0, stream>>>(src, dst, rowptr, cnt, esrc, E);
    scale_kernel<<<(N * 8 + 255) / 256, 256, 0, stream>>>(feats, outn, hsA, N);

    // L1: hsA->hsB ; L2: hsB->hsA ; L3: hsA->(pred d_out), hs_out unused
    const unsigned short* ins[3]  = {hsA, hsB, hsA};
    unsigned short*       outs[3] = {hsB, hsA, hsB};
    for (int l = 0; l < 3; ++l) {
        gcn_kernel<<<1024, 256, 0, stream>>>(
            rowptr, esrc, inn, rs, outn, ins[l],
            conv_W + (size_t)l * DD * DD, conv_b + (size_t)l * DD,
            res_W  + (size_t)l * DD * DD, res_b  + (size_t)l * DD,
            pred_W, pred_b,
            ln_g   + (size_t)l * DD,      ln_b   + (size_t)l * DD,
            outs[l], hfin, (float*)d_out,
            (l == 0) ? 1 : 0, (l == 2) ? 1 : 0, N);
    }
}